// Round 1
// baseline (1116.183 us; speedup 1.0000x reference)
//
#include <hip/hip_runtime.h>

#define DEV __device__ __forceinline__

typedef float f32x4 __attribute__((ext_vector_type(4)));
typedef short short8 __attribute__((ext_vector_type(8)));

DEV float gelu_f(float x) { return 0.5f * x * (1.f + erff(x * 0.70710678118654752f)); }

DEV short f2bf(float f) {
    union { float f; unsigned u; } c; c.f = f;
    unsigned r = (c.u + 0x7FFFu + ((c.u >> 16) & 1u)) >> 16;  // RNE
    return (short)r;
}

DEV float wred_sum(float v) {
    #pragma unroll
    for (int off = 1; off < 64; off <<= 1) v += __shfl_xor(v, off);
    return v;
}
DEV float wred_max(float v) {
    #pragma unroll
    for (int off = 1; off < 64; off <<= 1) v = fmaxf(v, __shfl_xor(v, off));
    return v;
}

// ---------------- embedding + positional encoding ----------------
__global__ __launch_bounds__(256) void k_embed(const int* __restrict__ tokens,
                                               const float* __restrict__ emb,
                                               float* __restrict__ x) {
    int n = blockIdx.x, d = threadIdx.x;
    int tok = tokens[n];
    float div = expf((float)((d >> 1) * 2) * -0.035977892079030837f); // -ln(10000)/256
    float arg = (float)n * div;
    float pe = (d & 1) ? cosf(arg) : sinf(arg);
    x[n * 256 + d] = emb[tok * 256 + d] + pe;
}

// ---------------- generic fp32 GEMM: out[n][m] = act(dot(A[n],W[m]) + bias[m]) ----
// A [N][K] (row stride K), W rows at stride ldw, out [N][M]. grid=(M/64, N/32), 256 thr.
__global__ __launch_bounds__(256) void k_gemm(const float* __restrict__ A,
                                              const float* __restrict__ W,
                                              const float* __restrict__ bias,
                                              float* __restrict__ out,
                                              int M, int K, int ldw, int act) {
    __shared__ __align__(16) float As[32][34];
    __shared__ __align__(16) float Bs[32][64];
    int m0 = blockIdx.x * 64, n0 = blockIdx.y * 32;
    int t = threadIdx.x;
    int tm = t & 15, tn = t >> 4;
    int a_n = t >> 3, a_k = (t & 7) << 2;
    int b_m = t >> 2, b_k = (t & 3) << 3;
    const float* Aptr = A + (size_t)(n0 + a_n) * K + a_k;
    const float* Wptr = W + (size_t)(m0 + b_m) * ldw + b_k;
    float acc[2][4];
    #pragma unroll
    for (int i = 0; i < 2; ++i)
        #pragma unroll
        for (int j = 0; j < 4; ++j) acc[i][j] = 0.f;

    for (int k0 = 0; k0 < K; k0 += 32) {
        float4 av  = *(const float4*)(Aptr + k0);
        float4 bv0 = *(const float4*)(Wptr + k0);
        float4 bv1 = *(const float4*)(Wptr + k0 + 4);
        __syncthreads();
        As[a_k + 0][a_n] = av.x;  As[a_k + 1][a_n] = av.y;
        As[a_k + 2][a_n] = av.z;  As[a_k + 3][a_n] = av.w;
        Bs[b_k + 0][b_m] = bv0.x; Bs[b_k + 1][b_m] = bv0.y;
        Bs[b_k + 2][b_m] = bv0.z; Bs[b_k + 3][b_m] = bv0.w;
        Bs[b_k + 4][b_m] = bv1.x; Bs[b_k + 5][b_m] = bv1.y;
        Bs[b_k + 6][b_m] = bv1.z; Bs[b_k + 7][b_m] = bv1.w;
        __syncthreads();
        #pragma unroll
        for (int kk = 0; kk < 32; ++kk) {
            float2 a2 = *(const float2*)&As[kk][tn * 2];
            float4 b4 = *(const float4*)&Bs[kk][tm * 4];
            acc[0][0] += a2.x * b4.x; acc[0][1] += a2.x * b4.y;
            acc[0][2] += a2.x * b4.z; acc[0][3] += a2.x * b4.w;
            acc[1][0] += a2.y * b4.x; acc[1][1] += a2.y * b4.y;
            acc[1][2] += a2.y * b4.z; acc[1][3] += a2.y * b4.w;
        }
    }
    float bb[4];
    #pragma unroll
    for (int j = 0; j < 4; ++j) bb[j] = bias ? bias[m0 + tm * 4 + j] : 0.f;
    #pragma unroll
    for (int i2 = 0; i2 < 2; ++i2) {
        int n = n0 + tn * 2 + i2;
        float rv[4];
        #pragma unroll
        for (int j = 0; j < 4; ++j) {
            float v = acc[i2][j] + bb[j];
            if (act == 1) v = fmaxf(v, 0.f);
            else if (act == 2) v = gelu_f(v);
            else if (act == 3) v = 1.f / (1.f + __expf(-v));
            rv[j] = v;
        }
        *(float4*)(out + (size_t)n * M + m0 + tm * 4) = make_float4(rv[0], rv[1], rv[2], rv[3]);
    }
}

// ---------------- transpose K-third of qkv into kt[c][n] (c=0..255) ----------------
__global__ __launch_bounds__(256) void k_transpose_k(const float* __restrict__ qkv,
                                                     float* __restrict__ kt) {
    __shared__ float tile[32][33];
    int c0 = blockIdx.x * 32, n0 = blockIdx.y * 32;
    int tx = threadIdx.x & 31, ty = threadIdx.x >> 5;
    #pragma unroll
    for (int k = 0; k < 4; ++k) {
        int n = n0 + ty + k * 8;
        tile[ty + k * 8][tx] = qkv[(size_t)n * 768 + 256 + c0 + tx];
    }
    __syncthreads();
    #pragma unroll
    for (int k = 0; k < 4; ++k) {
        int c = c0 + ty + k * 8;
        kt[(size_t)c * 512 + n0 + tx] = tile[tx][ty + k * 8];
    }
}

// ---------------- attention: one wave per (query i, head h) ----------------
__global__ __launch_bounds__(64) void k_attn(const float* __restrict__ qkv,
                                             const float* __restrict__ kt,
                                             float* __restrict__ obuf) {
    int i = blockIdx.x, h = blockIdx.y;
    int lane = threadIdx.x;
    __shared__ float p_lds[512];
    const float* qrow = qkv + (size_t)i * 768 + h * 32;
    float qv[32];
    #pragma unroll
    for (int d4 = 0; d4 < 8; ++d4) {
        float4 v = *(const float4*)(qrow + d4 * 4);
        qv[d4 * 4 + 0] = v.x; qv[d4 * 4 + 1] = v.y;
        qv[d4 * 4 + 2] = v.z; qv[d4 * 4 + 3] = v.w;
    }
    const float* kth = kt + (size_t)h * 32 * 512;
    float sc[8];
    #pragma unroll
    for (int t8 = 0; t8 < 8; ++t8) {
        int j = t8 * 64 + lane;
        float s = 0.f;
        #pragma unroll
        for (int d = 0; d < 32; ++d) s += qv[d] * kth[d * 512 + j];
        sc[t8] = s * 0.17677669529663687f; // 1/sqrt(32)
    }
    float m = sc[0];
    #pragma unroll
    for (int t8 = 1; t8 < 8; ++t8) m = fmaxf(m, sc[t8]);
    m = wred_max(m);
    float S = 0.f;
    #pragma unroll
    for (int t8 = 0; t8 < 8; ++t8) {
        float p = __expf(sc[t8] - m);
        p_lds[t8 * 64 + lane] = p;
        S += p;
    }
    S = wred_sum(S);
    __syncthreads();
    int d = lane & 31, half = lane >> 5;
    const float* vcol = qkv + 512 + h * 32 + d;
    float acc = 0.f;
    #pragma unroll 4
    for (int jj = 0; jj < 256; ++jj) {
        int j = half * 256 + jj;
        acc += p_lds[j] * vcol[(size_t)j * 768];
    }
    acc += __shfl_xor(acc, 32);
    if (lane < 32) obuf[(size_t)i * 256 + h * 32 + d] = acc * (1.f / S);
}

// ---------------- residual + LayerNorm (row-wise, one wave per row) ----------------
__global__ __launch_bounds__(64) void k_ln(const float* xr, const float* y,
                                           const float* __restrict__ g,
                                           const float* __restrict__ b, float* out) {
    int n = blockIdx.x, lane = threadIdx.x;
    float4 xv = *(const float4*)(xr + (size_t)n * 256 + lane * 4);
    float4 yv = *(const float4*)(y + (size_t)n * 256 + lane * 4);
    float t0 = xv.x + yv.x, t1 = xv.y + yv.y, t2 = xv.z + yv.z, t3 = xv.w + yv.w;
    float s = t0 + t1 + t2 + t3;
    float sq = t0 * t0 + t1 * t1 + t2 * t2 + t3 * t3;
    s = wred_sum(s);
    sq = wred_sum(sq);
    float mean = s * (1.f / 256.f);
    float var = sq * (1.f / 256.f) - mean * mean;
    float rstd = rsqrtf(var + 1e-5f);
    float4 gv = *(const float4*)(g + lane * 4);
    float4 bv = *(const float4*)(b + lane * 4);
    float4 r = make_float4((t0 - mean) * rstd * gv.x + bv.x,
                           (t1 - mean) * rstd * gv.y + bv.y,
                           (t2 - mean) * rstd * gv.z + bv.z,
                           (t3 - mean) * rstd * gv.w + bv.w);
    *(float4*)(out + (size_t)n * 256 + lane * 4) = r;
}

// ---------------- alpha head ----------------
__global__ __launch_bounds__(64) void k_alpha(const float* __restrict__ g,
                                              const float* __restrict__ A2,
                                              const float* __restrict__ a2b,
                                              float* __restrict__ alpha) {
    int n = blockIdx.x, lane = threadIdx.x;
    float4 gv = *(const float4*)(g + (size_t)n * 256 + lane * 4);
    float4 av = *(const float4*)(A2 + lane * 4);
    float s = gv.x * av.x + gv.y * av.y + gv.z * av.z + gv.w * av.w;
    s = wred_sum(s);
    if (lane == 0) {
        float ah = s + a2b[0];
        alpha[n] = 1.2f + 2.3f / (1.f + __expf(-ah));
    }
}

// ---------------- CSOCRG kernel smoothing: latent2 = norm-kern @ latent ----------------
__global__ __launch_bounds__(256) void k_kern(const float* __restrict__ latent,
                                              const float* __restrict__ alpha,
                                              float* __restrict__ out) {
    __shared__ float wl[512];
    __shared__ float partial[4];
    int i = blockIdx.x, t = threadIdx.x;
    float ai = alpha[i];
    float w0, w1;
    {
        int j = t;
        float dd = fabsf((float)(i - j)) + 1e-4f;
        float ap = 0.5f * (ai + alpha[j]);
        w0 = exp2f(-ap * __log2f(dd) - dd * 0.048089834696298776f); // log2(e)/30
        j = t + 256;
        dd = fabsf((float)(i - j)) + 1e-4f;
        ap = 0.5f * (ai + alpha[j]);
        w1 = exp2f(-ap * __log2f(dd) - dd * 0.048089834696298776f);
    }
    wl[t] = w0; wl[t + 256] = w1;
    float s = wred_sum(w0 + w1);
    if ((t & 63) == 0) partial[t >> 6] = s;
    __syncthreads();
    float S = partial[0] + partial[1] + partial[2] + partial[3];
    float inv = 1.f / (S + 1e-8f);
    float acc = 0.f;
    #pragma unroll 4
    for (int j = 0; j < 512; ++j) acc += wl[j] * latent[(size_t)j * 256 + t];
    out[(size_t)i * 256 + t] = acc * inv;
}

// ---------------- fp32 -> bf16 convert ----------------
__global__ __launch_bounds__(256) void k_cvt_bf16(const float* __restrict__ in,
                                                  short* __restrict__ outp, int n) {
    int i = blockIdx.x * 256 + threadIdx.x;
    if (i < n) outp[i] = f2bf(in[i]);
}

// ---------------- distogram: fused gelu(hi+hj) @ F2^T + f2b via bf16 MFMA ----------------
// grid = (32 j-tiles, 128 i-tiles), 256 threads (4 waves). wave w: i = i0+w, 16 j's.
__global__ __launch_bounds__(256) void k_disto(const float* __restrict__ hi,
                                               const float* __restrict__ hj,
                                               const short* __restrict__ F2bf,
                                               const float* __restrict__ f2b,
                                               float* __restrict__ out) {
    __shared__ __align__(16) float hjs[16][260];
    int jt = blockIdx.x, it = blockIdx.y;
    int j0 = jt * 16, i0 = it * 4;
    int t = threadIdx.x;
    for (int q = t; q < 1024; q += 256) {  // 16 rows x 64 float4
        int r = q >> 6, c = (q & 63) << 2;
        float4 v = *(const float4*)(hj + (size_t)(j0 + r) * 256 + c);
        *(float4*)&hjs[r][c] = v;
    }
    __syncthreads();
    int w = t >> 6, lane = t & 63;
    int cr = lane & 15, g = lane >> 4;
    int i = i0 + w;
    const float* hirow = hi + (size_t)i * 256;
    f32x4 acc0 = {0.f, 0.f, 0.f, 0.f}, acc1 = acc0, acc2 = acc0, acc3 = acc0;
    #pragma unroll
    for (int ks = 0; ks < 8; ++ks) {
        int kbase = ks * 32 + g * 8;
        float4 ha = *(const float4*)(hirow + kbase);
        float4 hb = *(const float4*)(hirow + kbase + 4);
        float4 ja = *(const float4*)&hjs[cr][kbase];
        float4 jb = *(const float4*)&hjs[cr][kbase + 4];
        short8 af;
        af[0] = f2bf(gelu_f(ha.x + ja.x));
        af[1] = f2bf(gelu_f(ha.y + ja.y));
        af[2] = f2bf(gelu_f(ha.z + ja.z));
        af[3] = f2bf(gelu_f(ha.w + ja.w));
        af[4] = f2bf(gelu_f(hb.x + jb.x));
        af[5] = f2bf(gelu_f(hb.y + jb.y));
        af[6] = f2bf(gelu_f(hb.z + jb.z));
        af[7] = f2bf(gelu_f(hb.w + jb.w));
        short8 b0 = *(const short8*)(F2bf + (size_t)(cr) * 256 + kbase);
        short8 b1 = *(const short8*)(F2bf + (size_t)(cr + 16) * 256 + kbase);
        short8 b2 = *(const short8*)(F2bf + (size_t)(cr + 32) * 256 + kbase);
        short8 b3 = *(const short8*)(F2bf + (size_t)(cr + 48) * 256 + kbase);
        acc0 = __builtin_amdgcn_mfma_f32_16x16x32_bf16(af, b0, acc0, 0, 0, 0);
        acc1 = __builtin_amdgcn_mfma_f32_16x16x32_bf16(af, b1, acc1, 0, 0, 0);
        acc2 = __builtin_amdgcn_mfma_f32_16x16x32_bf16(af, b2, acc2, 0, 0, 0);
        acc3 = __builtin_amdgcn_mfma_f32_16x16x32_bf16(af, b3, acc3, 0, 0, 0);
    }
    #pragma unroll
    for (int r = 0; r < 4; ++r) {
        int jl = g * 4 + r;  // D row = (lane>>4)*4 + reg (m89-verified)
        float* op = out + ((size_t)i * 512 + j0 + jl) * 64;
        op[cr]      = acc0[r] + f2b[cr];
        op[cr + 16] = acc1[r] + f2b[cr + 16];
        op[cr + 32] = acc2[r] + f2b[cr + 32];
        op[cr + 48] = acc3[r] + f2b[cr + 48];
    }
}

// ---------------- torsion head ----------------
__global__ __launch_bounds__(64) void k_torsion(const float* __restrict__ g,
                                                const float* __restrict__ T2,
                                                const float* __restrict__ t2b,
                                                float* __restrict__ phi,
                                                float* __restrict__ psi) {
    int n = blockIdx.x, lane = threadIdx.x;
    float4 gv = *(const float4*)(g + (size_t)n * 256 + lane * 4);
    float4 w0 = *(const float4*)(T2 + lane * 4);
    float4 w1 = *(const float4*)(T2 + 256 + lane * 4);
    float s0 = gv.x * w0.x + gv.y * w0.y + gv.z * w0.z + gv.w * w0.w;
    float s1 = gv.x * w1.x + gv.y * w1.y + gv.z * w1.z + gv.w * w1.w;
    s0 = wred_sum(s0);
    s1 = wred_sum(s1);
    if (lane == 0) {
        phi[n] = tanhf(s0 + t2b[0]) * 3.14159265358979323846f;
        psi[n] = tanhf(s1 + t2b[1]) * 3.14159265358979323846f;
    }
}

// ---------------- diffusion init (closed form) ----------------
__global__ __launch_bounds__(64) void k_diffusion(const float* __restrict__ latent,
                                                  const float* __restrict__ Cp,
                                                  const float* __restrict__ cpb,
                                                  const float* __restrict__ noise,
                                                  float* __restrict__ xc) {
    int n = blockIdx.x, lane = threadIdx.x;
    float4 lv = *(const float4*)(latent + (size_t)n * 256 + lane * 4);
    const float CN = 40320.0f / 16777216.0f;  // 8!/8^8
    float s[3];
    #pragma unroll
    for (int c = 0; c < 3; ++c) {
        float4 w = *(const float4*)(Cp + c * 256 + lane * 4);
        float v = lv.x * w.x + lv.y * w.y + lv.z * w.z + lv.w * w.w;
        s[c] = wred_sum(v);
    }
    if (lane == 0) {
        #pragma unroll
        for (int c = 0; c < 3; ++c) {
            float tg = s[c] + cpb[c];
            xc[n * 3 + c] = CN * noise[n * 3 + c] + (1.f - CN) * tg;
        }
    }
}

extern "C" void kernel_launch(void* const* d_in, const int* in_sizes, int n_in,
                              void* d_out, int out_size, void* d_ws, size_t ws_size,
                              hipStream_t stream) {
    const int*   tokens = (const int*)d_in[0];
    const float* emb  = (const float*)d_in[1];
    const float* Wqkv = (const float*)d_in[2];
    const float* bqkv = (const float*)d_in[3];
    const float* Wo   = (const float*)d_in[4];
    const float* bo   = (const float*)d_in[5];
    const float* g1   = (const float*)d_in[6];
    const float* be1  = (const float*)d_in[7];
    const float* W1   = (const float*)d_in[8];
    const float* b1   = (const float*)d_in[9];
    const float* W2   = (const float*)d_in[10];
    const float* b2   = (const float*)d_in[11];
    const float* g2   = (const float*)d_in[12];
    const float* be2  = (const float*)d_in[13];
    const float* A1   = (const float*)d_in[14];
    const float* a1b  = (const float*)d_in[15];
    const float* A2   = (const float*)d_in[16];
    const float* a2b  = (const float*)d_in[17];
    const float* Cf   = (const float*)d_in[18];
    const float* cb   = (const float*)d_in[19];
    const float* F1   = (const float*)d_in[20];
    const float* f1b  = (const float*)d_in[21];
    const float* F2   = (const float*)d_in[22];
    const float* f2b  = (const float*)d_in[23];
    const float* T1   = (const float*)d_in[24];
    const float* t1b  = (const float*)d_in[25];
    const float* T2   = (const float*)d_in[26];
    const float* t2b  = (const float*)d_in[27];
    const float* Cp   = (const float*)d_in[28];
    const float* cpb  = (const float*)d_in[29];
    const float* noise= (const float*)d_in[30];

    float* ws   = (float*)d_ws;
    float* x    = ws;                 // 131072
    float* qkv  = ws + 131072;        // 393216
    float* obuf = ws + 524288;        // 131072
    float* h1   = ws + 655360;        // 524288
    float* y2   = ws + 1179648;       // 131072
    float* gbuf = ws + 1310720;       // 131072
    float* hh   = ws + 1441792;       // 131072
    float* hi   = ws + 1572864;       // 131072
    float* hj   = ws + 1703936;       // 131072
    short* F2bf = (short*)(ws + 1835008); // 16384 shorts (8192 floats)
    float* kt   = ws + 1843200;       // 131072

    float* out = (float*)d_out;
    float* o_latent  = out;                // 131072
    float* o_alpha   = out + 131072;       // 512
    float* o_contact = out + 131584;       // 262144
    float* o_disto   = out + 393728;       // 16777216
    float* o_phi     = out + 17170944;     // 512
    float* o_psi     = out + 17171456;     // 512
    float* o_xc      = out + 17171968;     // 1536

    k_embed<<<512, 256, 0, stream>>>(tokens, emb, x);

    for (int l = 0; l < 6; ++l) {
        k_gemm<<<dim3(12, 16), 256, 0, stream>>>(x, Wqkv + (size_t)l * 768 * 256,
                                                 bqkv + l * 768, qkv, 768, 256, 256, 0);
        k_transpose_k<<<dim3(8, 16), 256, 0, stream>>>(qkv, kt);
        k_attn<<<dim3(512, 8), 64, 0, stream>>>(qkv, kt, obuf);
        k_gemm<<<dim3(4, 16), 256, 0, stream>>>(obuf, Wo + (size_t)l * 256 * 256,
                                                bo + l * 256, y2, 256, 256, 256, 0);
        k_ln<<<512, 64, 0, stream>>>(x, y2, g1 + l * 256, be1 + l * 256, x);
        k_gemm<<<dim3(16, 16), 256, 0, stream>>>(x, W1 + (size_t)l * 1024 * 256,
                                                 b1 + l * 1024, h1, 1024, 256, 256, 1);
        k_gemm<<<dim3(4, 16), 256, 0, stream>>>(h1, W2 + (size_t)l * 256 * 1024,
                                                b2 + l * 256, y2, 256, 1024, 1024, 0);
        k_ln<<<512, 64, 0, stream>>>(x, y2, g2 + l * 256, be2 + l * 256, x);
    }

    // alpha head (uses pre-kern latent x)
    k_gemm<<<dim3(4, 16), 256, 0, stream>>>(x, A1, a1b, gbuf, 256, 256, 256, 2);
    k_alpha<<<512, 64, 0, stream>>>(gbuf, A2, a2b, o_alpha);
    // CSOCRG smoothing -> latent output
    k_kern<<<512, 256, 0, stream>>>(x, o_alpha, o_latent);
    // contact head
    k_gemm<<<dim3(4, 16), 256, 0, stream>>>(o_latent, Cf, cb, hh, 256, 256, 256, 0);
    k_gemm<<<dim3(8, 16), 256, 0, stream>>>(hh, hh, nullptr, o_contact, 512, 256, 256, 3);
    // distogram head
    k_gemm<<<dim3(4, 16), 256, 0, stream>>>(o_latent, F1, f1b, hi, 256, 256, 512, 0);
    k_gemm<<<dim3(4, 16), 256, 0, stream>>>(o_latent, F1 + 256, nullptr, hj, 256, 256, 512, 0);
    k_cvt_bf16<<<64, 256, 0, stream>>>(F2, F2bf, 16384);
    k_disto<<<dim3(32, 128), 256, 0, stream>>>(hi, hj, F2bf, f2b, o_disto);
    // torsion head
    k_gemm<<<dim3(4, 16), 256, 0, stream>>>(o_latent, T1, t1b, gbuf, 256, 256, 256, 2);
    k_torsion<<<512, 64, 0, stream>>>(gbuf, T2, t2b, o_phi, o_psi);
    // diffusion init
    k_diffusion<<<512, 64, 0, stream>>>(o_latent, Cp, cpb, noise, o_xc);
}

// Round 3
// 824.865 us; speedup vs baseline: 1.3532x; 1.3532x over previous
//
#include <hip/hip_runtime.h>

#define DEV __device__ __forceinline__

typedef float f32x4 __attribute__((ext_vector_type(4)));
typedef short short8 __attribute__((ext_vector_type(8)));
typedef short short4v __attribute__((ext_vector_type(4)));

DEV short f2bf(float f) {
    union { float f; unsigned u; } c; c.f = f;
    unsigned r = (c.u + 0x7FFFu + ((c.u >> 16) & 1u)) >> 16;  // RNE
    return (short)r;
}

// tanh-approx gelu: max |err| vs erf-gelu ~2e-4, ~12 VALU inst
DEV float gelu_t(float x) {
    float x2 = x * x;
    float y = x * (0.7978845608f + 0.0356774081f * x2);
    float e = __expf(-2.f * fabsf(y));
    float t = 1.f - 2.f * e / (1.f + e);          // tanh(|y|)
    t = copysignf(t, y);
    return 0.5f * x * (1.f + t);
}

DEV float wred_sum(float v) {
    #pragma unroll
    for (int off = 1; off < 64; off <<= 1) v += __shfl_xor(v, off);
    return v;
}
DEV float wred_max(float v) {
    #pragma unroll
    for (int off = 1; off < 64; off <<= 1) v = fmaxf(v, __shfl_xor(v, off));
    return v;
}

// ---------------- bulk fp32 -> bf16 conversion (9 segments) ----------------
struct CvtPack {
    const float* s[9];
    short* d[9];
    int n[9];
};
__global__ __launch_bounds__(256) void k_cvt_all(CvtPack p) {
    #pragma unroll 1
    for (int seg = 0; seg < 9; ++seg) {
        int n4 = p.n[seg] >> 2;
        const float4* src = (const float4*)p.s[seg];
        short4v* dst = (short4v*)p.d[seg];
        for (int i = blockIdx.x * 256 + threadIdx.x; i < n4; i += gridDim.x * 256) {
            float4 v = src[i];
            short4v o;
            o[0] = f2bf(v.x); o[1] = f2bf(v.y); o[2] = f2bf(v.z); o[3] = f2bf(v.w);
            dst[i] = o;
        }
    }
}

// ---------------- embedding + positional encoding (fp32 + bf16) ----------------
__global__ __launch_bounds__(256) void k_embed(const int* __restrict__ tokens,
                                               const float* __restrict__ emb,
                                               float* __restrict__ x,
                                               short* __restrict__ xb) {
    int n = blockIdx.x, d = threadIdx.x;
    int tok = tokens[n];
    float div = expf((float)((d >> 1) * 2) * -0.035977892079030837f); // -ln(10000)/256
    float arg = (float)n * div;
    float pe = (d & 1) ? cosf(arg) : sinf(arg);
    float v = emb[tok * 256 + d] + pe;
    x[n * 256 + d] = v;
    xb[n * 256 + d] = f2bf(v);
}

// ---------------- bf16 MFMA GEMM: out[n][m] = act(dot(A[n],W[m]) + bias[m]) ------
// A bf16 [N][K] row-major, W bf16 rows at stride ldw. 1 wave computes 32x32.
// grid = (M/32, N/32), 64 threads. Optional fp32 out, bf16 out, kt transpose
// (cols 256..511 -> kt[(m-256)*512+row], fp32).
__global__ __launch_bounds__(64) void k_gemm_bf(const short* __restrict__ A,
                                                const short* __restrict__ W,
                                                const float* __restrict__ bias,
                                                float* __restrict__ outf,
                                                short* __restrict__ outb,
                                                float* __restrict__ kt,
                                                int M, int K, int ldw, int act) {
    int m0 = blockIdx.x * 32, n0 = blockIdx.y * 32;
    int lane = threadIdx.x;
    int cr = lane & 15, g = lane >> 4;
    const short* a0 = A + (size_t)(n0 + cr) * K + g * 8;
    const short* a1 = a0 + (size_t)16 * K;
    const short* b0 = W + (size_t)(m0 + cr) * ldw + g * 8;
    const short* b1 = b0 + (size_t)16 * ldw;
    f32x4 acc00 = {0.f,0.f,0.f,0.f}, acc01 = acc00, acc10 = acc00, acc11 = acc00;
    #pragma unroll 4
    for (int k = 0; k < K; k += 32) {
        short8 av0 = *(const short8*)(a0 + k);
        short8 av1 = *(const short8*)(a1 + k);
        short8 bv0 = *(const short8*)(b0 + k);
        short8 bv1 = *(const short8*)(b1 + k);
        acc00 = __builtin_amdgcn_mfma_f32_16x16x32_bf16(av0, bv0, acc00, 0, 0, 0);
        acc01 = __builtin_amdgcn_mfma_f32_16x16x32_bf16(av0, bv1, acc01, 0, 0, 0);
        acc10 = __builtin_amdgcn_mfma_f32_16x16x32_bf16(av1, bv0, acc10, 0, 0, 0);
        acc11 = __builtin_amdgcn_mfma_f32_16x16x32_bf16(av1, bv1, acc11, 0, 0, 0);
    }
    float bb0 = bias ? bias[m0 + cr] : 0.f;
    float bb1 = bias ? bias[m0 + 16 + cr] : 0.f;
    #pragma unroll
    for (int fi = 0; fi < 2; ++fi) {
        #pragma unroll
        for (int r = 0; r < 4; ++r) {
            int row = n0 + fi * 16 + g * 4 + r;
            #pragma unroll
            for (int fj = 0; fj < 2; ++fj) {
                float v = (fi == 0 ? (fj == 0 ? acc00[r] : acc01[r])
                                   : (fj == 0 ? acc10[r] : acc11[r]));
                v += (fj == 0 ? bb0 : bb1);
                if (act == 1) v = fmaxf(v, 0.f);
                else if (act == 2) v = gelu_t(v);
                else if (act == 3) v = 1.f / (1.f + __expf(-v));
                int m = m0 + fj * 16 + cr;
                if (outf) outf[(size_t)row * M + m] = v;
                if (outb) outb[(size_t)row * M + m] = f2bf(v);
                if (kt && m >= 256 && m < 512) kt[(size_t)(m - 256) * 512 + row] = v;
            }
        }
    }
}

// ---------------- attention: one wave per (query i, head h) ----------------
__global__ __launch_bounds__(64) void k_attn(const float* __restrict__ qkv,
                                             const float* __restrict__ kt,
                                             float* __restrict__ obuf,
                                             short* __restrict__ obuf_bf) {
    int i = blockIdx.x, h = blockIdx.y;
    int lane = threadIdx.x;
    __shared__ float p_lds[512];
    const float* qrow = qkv + (size_t)i * 768 + h * 32;
    float qv[32];
    #pragma unroll
    for (int d4 = 0; d4 < 8; ++d4) {
        float4 v = *(const float4*)(qrow + d4 * 4);
        qv[d4 * 4 + 0] = v.x; qv[d4 * 4 + 1] = v.y;
        qv[d4 * 4 + 2] = v.z; qv[d4 * 4 + 3] = v.w;
    }
    const float* kth = kt + (size_t)h * 32 * 512;
    float sc[8];
    #pragma unroll
    for (int t8 = 0; t8 < 8; ++t8) {
        int j = t8 * 64 + lane;
        float s = 0.f;
        #pragma unroll
        for (int d = 0; d < 32; ++d) s += qv[d] * kth[d * 512 + j];
        sc[t8] = s * 0.17677669529663687f; // 1/sqrt(32)
    }
    float m = sc[0];
    #pragma unroll
    for (int t8 = 1; t8 < 8; ++t8) m = fmaxf(m, sc[t8]);
    m = wred_max(m);
    float S = 0.f;
    #pragma unroll
    for (int t8 = 0; t8 < 8; ++t8) {
        float p = __expf(sc[t8] - m);
        p_lds[t8 * 64 + lane] = p;
        S += p;
    }
    S = wred_sum(S);
    __syncthreads();
    int d = lane & 31, half = lane >> 5;
    const float* vcol = qkv + 512 + h * 32 + d;
    float acc = 0.f;
    #pragma unroll 4
    for (int jj = 0; jj < 256; ++jj) {
        int j = half * 256 + jj;
        acc += p_lds[j] * vcol[(size_t)j * 768];
    }
    acc += __shfl_xor(acc, 32);
    if (lane < 32) {
        float o = acc * (1.f / S);
        obuf[(size_t)i * 256 + h * 32 + d] = o;
        obuf_bf[(size_t)i * 256 + h * 32 + d] = f2bf(o);
    }
}

// ---------------- residual + LayerNorm (fp32 + bf16 out) ----------------
__global__ __launch_bounds__(64) void k_ln(const float* xr, const float* y,
                                           const float* __restrict__ g,
                                           const float* __restrict__ b,
                                           float* out, short* outb) {
    int n = blockIdx.x, lane = threadIdx.x;
    float4 xv = *(const float4*)(xr + (size_t)n * 256 + lane * 4);
    float4 yv = *(const float4*)(y + (size_t)n * 256 + lane * 4);
    float t0 = xv.x + yv.x, t1 = xv.y + yv.y, t2 = xv.z + yv.z, t3 = xv.w + yv.w;
    float s = t0 + t1 + t2 + t3;
    float sq = t0 * t0 + t1 * t1 + t2 * t2 + t3 * t3;
    s = wred_sum(s);
    sq = wred_sum(sq);
    float mean = s * (1.f / 256.f);
    float var = sq * (1.f / 256.f) - mean * mean;
    float rstd = rsqrtf(var + 1e-5f);
    float4 gv = *(const float4*)(g + lane * 4);
    float4 bv = *(const float4*)(b + lane * 4);
    float r0 = (t0 - mean) * rstd * gv.x + bv.x;
    float r1 = (t1 - mean) * rstd * gv.y + bv.y;
    float r2 = (t2 - mean) * rstd * gv.z + bv.z;
    float r3 = (t3 - mean) * rstd * gv.w + bv.w;
    *(float4*)(out + (size_t)n * 256 + lane * 4) = make_float4(r0, r1, r2, r3);
    short4v ob; ob[0] = f2bf(r0); ob[1] = f2bf(r1); ob[2] = f2bf(r2); ob[3] = f2bf(r3);
    *(short4v*)(outb + (size_t)n * 256 + lane * 4) = ob;
}

// ---------------- alpha head ----------------
__global__ __launch_bounds__(64) void k_alpha(const float* __restrict__ g,
                                              const float* __restrict__ A2,
                                              const float* __restrict__ a2b,
                                              float* __restrict__ alpha) {
    int n = blockIdx.x, lane = threadIdx.x;
    float4 gv = *(const float4*)(g + (size_t)n * 256 + lane * 4);
    float4 av = *(const float4*)(A2 + lane * 4);
    float s = gv.x * av.x + gv.y * av.y + gv.z * av.z + gv.w * av.w;
    s = wred_sum(s);
    if (lane == 0) {
        float ah = s + a2b[0];
        alpha[n] = 1.2f + 2.3f / (1.f + __expf(-ah));
    }
}

// ---------------- CSOCRG kernel smoothing ----------------
__global__ __launch_bounds__(256) void k_kern(const float* __restrict__ latent,
                                              const float* __restrict__ alpha,
                                              float* __restrict__ out,
                                              short* __restrict__ outb) {
    __shared__ float wl[512];
    __shared__ float partial[4];
    int i = blockIdx.x, t = threadIdx.x;
    float ai = alpha[i];
    float w0, w1;
    {
        int j = t;
        float dd = fabsf((float)(i - j)) + 1e-4f;
        float ap = 0.5f * (ai + alpha[j]);
        w0 = exp2f(-ap * __log2f(dd) - dd * 0.048089834696298776f); // log2(e)/30
        j = t + 256;
        dd = fabsf((float)(i - j)) + 1e-4f;
        ap = 0.5f * (ai + alpha[j]);
        w1 = exp2f(-ap * __log2f(dd) - dd * 0.048089834696298776f);
    }
    wl[t] = w0; wl[t + 256] = w1;
    float s = wred_sum(w0 + w1);
    if ((t & 63) == 0) partial[t >> 6] = s;
    __syncthreads();
    float S = partial[0] + partial[1] + partial[2] + partial[3];
    float inv = 1.f / (S + 1e-8f);
    float acc = 0.f;
    #pragma unroll 4
    for (int j = 0; j < 512; ++j) acc += wl[j] * latent[(size_t)j * 256 + t];
    float v = acc * inv;
    out[(size_t)i * 256 + t] = v;
    outb[(size_t)i * 256 + t] = f2bf(v);
}

// ---------------- distogram v2: 4 i's per wave, F2 frags reused ----------------
// grid = (32 jt, 32 it), 256 threads (4 waves). wave w: i = it*16 + w*4 + 0..3.
__global__ __launch_bounds__(256) void k_disto2(const float* __restrict__ hi,
                                                const float* __restrict__ hj,
                                                const short* __restrict__ F2bf,
                                                const float* __restrict__ f2b,
                                                float* __restrict__ out) {
    __shared__ __align__(16) float hjs[16][260];
    int jt = blockIdx.x, it = blockIdx.y;
    int j0 = jt * 16;
    int t = threadIdx.x;
    for (int q = t; q < 1024; q += 256) {  // 16 rows x 64 float4
        int r = q >> 6, c = (q & 63) << 2;
        float4 v = *(const float4*)(hj + (size_t)(j0 + r) * 256 + c);
        *(float4*)&hjs[r][c] = v;
    }
    __syncthreads();
    int w = t >> 6, lane = t & 63;
    int cr = lane & 15, g = lane >> 4;
    int i0 = it * 16 + w * 4;
    float bb[4];
    #pragma unroll
    for (int c = 0; c < 4; ++c) bb[c] = f2b[c * 16 + cr];
    f32x4 acc[4][4];
    #pragma unroll
    for (int ii = 0; ii < 4; ++ii)
        #pragma unroll
        for (int c = 0; c < 4; ++c) acc[ii][c] = (f32x4){0.f,0.f,0.f,0.f};
    #pragma unroll 1
    for (int ks = 0; ks < 8; ++ks) {
        int kb = ks * 32 + g * 8;
        short8 B[4];
        #pragma unroll
        for (int c = 0; c < 4; ++c)
            B[c] = *(const short8*)(F2bf + (size_t)(c * 16 + cr) * 256 + kb);
        float4 ja = *(const float4*)&hjs[cr][kb];
        float4 jb = *(const float4*)&hjs[cr][kb + 4];
        #pragma unroll
        for (int ii = 0; ii < 4; ++ii) {
            const float* hr = hi + (size_t)(i0 + ii) * 256 + kb;
            float4 ha = *(const float4*)(hr);
            float4 hb = *(const float4*)(hr + 4);
            short8 af;
            af[0] = f2bf(gelu_t(ha.x + ja.x));
            af[1] = f2bf(gelu_t(ha.y + ja.y));
            af[2] = f2bf(gelu_t(ha.z + ja.z));
            af[3] = f2bf(gelu_t(ha.w + ja.w));
            af[4] = f2bf(gelu_t(hb.x + jb.x));
            af[5] = f2bf(gelu_t(hb.y + jb.y));
            af[6] = f2bf(gelu_t(hb.z + jb.z));
            af[7] = f2bf(gelu_t(hb.w + jb.w));
            #pragma unroll
            for (int c = 0; c < 4; ++c)
                acc[ii][c] = __builtin_amdgcn_mfma_f32_16x16x32_bf16(af, B[c], acc[ii][c], 0, 0, 0);
        }
    }
    #pragma unroll
    for (int ii = 0; ii < 4; ++ii) {
        #pragma unroll
        for (int r = 0; r < 4; ++r) {
            int jl = g * 4 + r;
            float* op = out + ((size_t)(i0 + ii) * 512 + j0 + jl) * 64;
            op[cr]      = acc[ii][0][r] + bb[0];
            op[cr + 16] = acc[ii][1][r] + bb[1];
            op[cr + 32] = acc[ii][2][r] + bb[2];
            op[cr + 48] = acc[ii][3][r] + bb[3];
        }
    }
}

// ---------------- torsion head ----------------
__global__ __launch_bounds__(64) void k_torsion(const float* __restrict__ g,
                                                const float* __restrict__ T2,
                                                const float* __restrict__ t2b,
                                                float* __restrict__ phi,
                                                float* __restrict__ psi) {
    int n = blockIdx.x, lane = threadIdx.x;
    float4 gv = *(const float4*)(g + (size_t)n * 256 + lane * 4);
    float4 w0 = *(const float4*)(T2 + lane * 4);
    float4 w1 = *(const float4*)(T2 + 256 + lane * 4);
    float s0 = gv.x * w0.x + gv.y * w0.y + gv.z * w0.z + gv.w * w0.w;
    float s1 = gv.x * w1.x + gv.y * w1.y + gv.z * w1.z + gv.w * w1.w;
    s0 = wred_sum(s0);
    s1 = wred_sum(s1);
    if (lane == 0) {
        phi[n] = tanhf(s0 + t2b[0]) * 3.14159265358979323846f;
        psi[n] = tanhf(s1 + t2b[1]) * 3.14159265358979323846f;
    }
}

// ---------------- diffusion init (closed form) ----------------
__global__ __launch_bounds__(64) void k_diffusion(const float* __restrict__ latent,
                                                  const float* __restrict__ Cp,
                                                  const float* __restrict__ cpb,
                                                  const float* __restrict__ noise,
                                                  float* __restrict__ xc) {
    int n = blockIdx.x, lane = threadIdx.x;
    float4 lv = *(const float4*)(latent + (size_t)n * 256 + lane * 4);
    const float CN = 40320.0f / 16777216.0f;  // 8!/8^8
    float s[3];
    #pragma unroll
    for (int c = 0; c < 3; ++c) {
        float4 w = *(const float4*)(Cp + c * 256 + lane * 4);
        float v = lv.x * w.x + lv.y * w.y + lv.z * w.z + lv.w * w.w;
        s[c] = wred_sum(v);
    }
    if (lane == 0) {
        #pragma unroll
        for (int c = 0; c < 3; ++c) {
            float tg = s[c] + cpb[c];
            xc[n * 3 + c] = CN * noise[n * 3 + c] + (1.f - CN) * tg;
        }
    }
}

extern "C" void kernel_launch(void* const* d_in, const int* in_sizes, int n_in,
                              void* d_out, int out_size, void* d_ws, size_t ws_size,
                              hipStream_t stream) {
    const int*   tokens = (const int*)d_in[0];
    const float* emb  = (const float*)d_in[1];
    const float* Wqkv = (const float*)d_in[2];
    const float* bqkv = (const float*)d_in[3];
    const float* Wo   = (const float*)d_in[4];
    const float* bo   = (const float*)d_in[5];
    const float* g1   = (const float*)d_in[6];
    const float* be1  = (const float*)d_in[7];
    const float* W1   = (const float*)d_in[8];
    const float* b1   = (const float*)d_in[9];
    const float* W2   = (const float*)d_in[10];
    const float* b2   = (const float*)d_in[11];
    const float* g2   = (const float*)d_in[12];
    const float* be2  = (const float*)d_in[13];
    const float* A1   = (const float*)d_in[14];
    const float* a1b  = (const float*)d_in[15];
    const float* A2   = (const float*)d_in[16];
    const float* a2b  = (const float*)d_in[17];
    const float* Cf   = (const float*)d_in[18];
    const float* cb   = (const float*)d_in[19];
    const float* F1   = (const float*)d_in[20];
    const float* f1b  = (const float*)d_in[21];
    const float* F2   = (const float*)d_in[22];
    const float* f2b  = (const float*)d_in[23];
    const float* T1   = (const float*)d_in[24];
    const float* t1b  = (const float*)d_in[25];
    const float* T2   = (const float*)d_in[26];
    const float* t2b  = (const float*)d_in[27];
    const float* Cp   = (const float*)d_in[28];
    const float* cpb  = (const float*)d_in[29];
    const float* noise= (const float*)d_in[30];

    float* ws   = (float*)d_ws;
    float* x    = ws;                 // 131072
    float* qkv  = ws + 131072;        // 393216
    float* obuf = ws + 524288;        // 131072
    float* y2   = ws + 655360;        // 131072
    float* gbuf = ws + 786432;        // 131072
    float* hi   = ws + 917504;        // 131072
    float* hj   = ws + 1048576;       // 131072
    float* kt   = ws + 1179648;       // 131072
    short* S    = (short*)(ws + 1310720);
    short* x_bf    = S;               // 131072 shorts
    short* obuf_bf = S + 131072;      // 131072
    short* h1_bf   = S + 262144;      // 524288
    short* hh_bf   = S + 786432;      // 131072
    short* lat_bf  = S + 917504;      // 131072
    short* F2bf    = S + 1048576;     // 16384
    short* Wqkv_bf = S + 1064960;     // 1179648
    short* Wo_bf   = S + 2244608;     // 393216
    short* W1_bf   = S + 2637824;     // 1572864
    short* W2_bf   = S + 4210688;     // 1572864
    short* A1_bf   = S + 5783552;     // 65536
    short* Cf_bf   = S + 5849088;     // 65536
    short* F1_bf   = S + 5914624;     // 131072
    short* T1_bf   = S + 6045696;     // 65536

    float* out = (float*)d_out;
    float* o_latent  = out;                // 131072
    float* o_alpha   = out + 131072;       // 512
    float* o_contact = out + 131584;       // 262144
    float* o_disto   = out + 393728;       // 16777216
    float* o_phi     = out + 17170944;     // 512
    float* o_psi     = out + 17171456;     // 512
    float* o_xc      = out + 17171968;     // 1536

    CvtPack p;
    p.s[0] = Wqkv; p.d[0] = Wqkv_bf; p.n[0] = 1179648;
    p.s[1] = Wo;   p.d[1] = Wo_bf;   p.n[1] = 393216;
    p.s[2] = W1;   p.d[2] = W1_bf;   p.n[2] = 1572864;
    p.s[3] = W2;   p.d[3] = W2_bf;   p.n[3] = 1572864;
    p.s[4] = A1;   p.d[4] = A1_bf;   p.n[4] = 65536;
    p.s[5] = Cf;   p.d[5] = Cf_bf;   p.n[5] = 65536;
    p.s[6] = F1;   p.d[6] = F1_bf;   p.n[6] = 131072;
    p.s[7] = T1;   p.d[7] = T1_bf;   p.n[7] = 65536;
    p.s[8] = F2;   p.d[8] = F2bf;    p.n[8] = 16384;
    k_cvt_all<<<512, 256, 0, stream>>>(p);

    k_embed<<<512, 256, 0, stream>>>(tokens, emb, x, x_bf);

    for (int l = 0; l < 6; ++l) {
        k_gemm_bf<<<dim3(24, 16), 64, 0, stream>>>(x_bf, Wqkv_bf + (size_t)l * 196608,
            bqkv + l * 768, qkv, nullptr, kt, 768, 256, 256, 0);
        k_attn<<<dim3(512, 8), 64, 0, stream>>>(qkv, kt, obuf, obuf_bf);
        k_gemm_bf<<<dim3(8, 16), 64, 0, stream>>>(obuf_bf, Wo_bf + (size_t)l * 65536,
            bo + l * 256, y2, nullptr, nullptr, 256, 256, 256, 0);
        k_ln<<<512, 64, 0, stream>>>(x, y2, g1 + l * 256, be1 + l * 256, x, x_bf);
        k_gemm_bf<<<dim3(32, 16), 64, 0, stream>>>(x_bf, W1_bf + (size_t)l * 262144,
            b1 + l * 1024, nullptr, h1_bf, nullptr, 1024, 256, 256, 1);
        k_gemm_bf<<<dim3(8, 16), 64, 0, stream>>>(h1_bf, W2_bf + (size_t)l * 262144,
            b2 + l * 256, y2, nullptr, nullptr, 256, 1024, 1024, 0);
        k_ln<<<512, 64, 0, stream>>>(x, y2, g2 + l * 256, be2 + l * 256, x, x_bf);
    }

    // alpha head (pre-smoothing latent)
    k_gemm_bf<<<dim3(8, 16), 64, 0, stream>>>(x_bf, A1_bf, a1b, gbuf, nullptr, nullptr,
                                              256, 256, 256, 2);
    k_alpha<<<512, 64, 0, stream>>>(gbuf, A2, a2b, o_alpha);
    // CSOCRG smoothing -> latent output (fp32 + bf16)
    k_kern<<<512, 256, 0, stream>>>(x, o_alpha, o_latent, lat_bf);
    // contact head
    k_gemm_bf<<<dim3(8, 16), 64, 0, stream>>>(lat_bf, Cf_bf, cb, nullptr, hh_bf, nullptr,
                                              256, 256, 256, 0);
    k_gemm_bf<<<dim3(16, 16), 64, 0, stream>>>(hh_bf, hh_bf, nullptr, o_contact, nullptr,
                                               nullptr, 512, 256, 256, 3);
    // distogram head
    k_gemm_bf<<<dim3(8, 16), 64, 0, stream>>>(lat_bf, F1_bf, f1b, hi, nullptr, nullptr,
                                              256, 256, 512, 0);
    k_gemm_bf<<<dim3(8, 16), 64, 0, stream>>>(lat_bf, F1_bf + 256, nullptr, hj, nullptr,
                                              nullptr, 256, 256, 512, 0);
    k_disto2<<<dim3(32, 32), 256, 0, stream>>>(hi, hj, F2bf, f2b, o_disto);
    // torsion head
    k_gemm_bf<<<dim3(8, 16), 64, 0, stream>>>(lat_bf, T1_bf, t1b, gbuf, nullptr, nullptr,
                                              256, 256, 256, 2);
    k_torsion<<<512, 64, 0, stream>>>(gbuf, T2, t2b, o_phi, o_psi);
    // diffusion init
    k_diffusion<<<512, 64, 0, stream>>>(o_latent, Cp, cpb, noise, o_xc);
}

// Round 4
// 470.842 us; speedup vs baseline: 2.3706x; 1.7519x over previous
//
#include <hip/hip_runtime.h>

#define DEV __device__ __forceinline__

typedef float f32x4 __attribute__((ext_vector_type(4)));
typedef short short8 __attribute__((ext_vector_type(8)));
typedef short short4v __attribute__((ext_vector_type(4)));

DEV short f2bf(float f) {
    union { float f; unsigned u; } c; c.f = f;
    unsigned r = (c.u + 0x7FFFu + ((c.u >> 16) & 1u)) >> 16;  // RNE
    return (short)r;
}

// tanh-approx gelu: max |err| vs erf-gelu ~2e-4, ~12 VALU inst
DEV float gelu_t(float x) {
    float x2 = x * x;
    float y = x * (0.7978845608f + 0.0356774081f * x2);
    float e = __expf(-2.f * fabsf(y));
    float t = 1.f - 2.f * e / (1.f + e);          // tanh(|y|)
    t = copysignf(t, y);
    return 0.5f * x * (1.f + t);
}

DEV float wred_sum(float v) {
    #pragma unroll
    for (int off = 1; off < 64; off <<= 1) v += __shfl_xor(v, off);
    return v;
}
DEV float wred_max(float v) {
    #pragma unroll
    for (int off = 1; off < 64; off <<= 1) v = fmaxf(v, __shfl_xor(v, off));
    return v;
}

// ---------------- bulk fp32 -> bf16 conversion (9 segments) ----------------
struct CvtPack {
    const float* s[9];
    short* d[9];
    int n[9];
};
__global__ __launch_bounds__(256) void k_cvt_all(CvtPack p) {
    #pragma unroll 1
    for (int seg = 0; seg < 9; ++seg) {
        int n4 = p.n[seg] >> 2;
        const float4* src = (const float4*)p.s[seg];
        short4v* dst = (short4v*)p.d[seg];
        for (int i = blockIdx.x * 256 + threadIdx.x; i < n4; i += gridDim.x * 256) {
            float4 v = src[i];
            short4v o;
            o[0] = f2bf(v.x); o[1] = f2bf(v.y); o[2] = f2bf(v.z); o[3] = f2bf(v.w);
            dst[i] = o;
        }
    }
}

// ---------------- embedding + positional encoding (fp32 + bf16) ----------------
__global__ __launch_bounds__(256) void k_embed(const int* __restrict__ tokens,
                                               const float* __restrict__ emb,
                                               float* __restrict__ x,
                                               short* __restrict__ xb) {
    int n = blockIdx.x, d = threadIdx.x;
    int tok = tokens[n];
    float div = expf((float)((d >> 1) * 2) * -0.035977892079030837f); // -ln(10000)/256
    float arg = (float)n * div;
    float pe = (d & 1) ? cosf(arg) : sinf(arg);
    float v = emb[tok * 256 + d] + pe;
    x[n * 256 + d] = v;
    xb[n * 256 + d] = f2bf(v);
}

// ---------------- bf16 MFMA GEMM: out[n][m] = act(dot(A[n],W[m]) + bias[m]) ------
// A bf16 [N][K] row-major, W bf16 rows at stride ldw. 1 wave computes 32x32.
// grid = (M/32, N/32), 64 threads.
__global__ __launch_bounds__(64) void k_gemm_bf(const short* __restrict__ A,
                                                const short* __restrict__ W,
                                                const float* __restrict__ bias,
                                                float* __restrict__ outf,
                                                short* __restrict__ outb,
                                                int M, int K, int ldw, int act) {
    int m0 = blockIdx.x * 32, n0 = blockIdx.y * 32;
    int lane = threadIdx.x;
    int cr = lane & 15, g = lane >> 4;
    const short* a0 = A + (size_t)(n0 + cr) * K + g * 8;
    const short* a1 = a0 + (size_t)16 * K;
    const short* b0 = W + (size_t)(m0 + cr) * ldw + g * 8;
    const short* b1 = b0 + (size_t)16 * ldw;
    f32x4 acc00 = {0.f,0.f,0.f,0.f}, acc01 = acc00, acc10 = acc00, acc11 = acc00;
    #pragma unroll 4
    for (int k = 0; k < K; k += 32) {
        short8 av0 = *(const short8*)(a0 + k);
        short8 av1 = *(const short8*)(a1 + k);
        short8 bv0 = *(const short8*)(b0 + k);
        short8 bv1 = *(const short8*)(b1 + k);
        acc00 = __builtin_amdgcn_mfma_f32_16x16x32_bf16(av0, bv0, acc00, 0, 0, 0);
        acc01 = __builtin_amdgcn_mfma_f32_16x16x32_bf16(av0, bv1, acc01, 0, 0, 0);
        acc10 = __builtin_amdgcn_mfma_f32_16x16x32_bf16(av1, bv0, acc10, 0, 0, 0);
        acc11 = __builtin_amdgcn_mfma_f32_16x16x32_bf16(av1, bv1, acc11, 0, 0, 0);
    }
    float bb0 = bias ? bias[m0 + cr] : 0.f;
    float bb1 = bias ? bias[m0 + 16 + cr] : 0.f;
    #pragma unroll
    for (int fi = 0; fi < 2; ++fi) {
        #pragma unroll
        for (int r = 0; r < 4; ++r) {
            int row = n0 + fi * 16 + g * 4 + r;
            #pragma unroll
            for (int fj = 0; fj < 2; ++fj) {
                float v = (fi == 0 ? (fj == 0 ? acc00[r] : acc01[r])
                                   : (fj == 0 ? acc10[r] : acc11[r]));
                v += (fj == 0 ? bb0 : bb1);
                if (act == 1) v = fmaxf(v, 0.f);
                else if (act == 2) v = gelu_t(v);
                else if (act == 3) v = 1.f / (1.f + __expf(-v));
                int m = m0 + fj * 16 + cr;
                if (outf) outf[(size_t)row * M + m] = v;
                if (outb) outb[(size_t)row * M + m] = f2bf(v);
            }
        }
    }
}

// ---------------- MFMA flash attention ----------------
// qkvb bf16 [512][768] (q|k|v per row). Block = 128 thr (2 waves), each wave
// owns 16 queries; grid (8 heads, 16 qtiles of 32). dh=32, scale 1/sqrt(32).
__global__ __launch_bounds__(128) void k_attn2(const short* __restrict__ qkvb,
                                               short* __restrict__ obuf_bf) {
    __shared__ __align__(16) short Vt[32][520];   // V^T per head, bf16
    __shared__ __align__(16) short Pb[2][16][40]; // per-wave P transpose buffer
    int h = blockIdx.x, qt = blockIdx.y;
    int t = threadIdx.x;
    // stage V^T: Vt[d][n] = V[n][d]
    for (int q = t; q < 4096; q += 128) {   // 512 n x 8 groups of 4 d
        int n = q >> 3, d4 = (q & 7) << 2;
        short4v v = *(const short4v*)(qkvb + (size_t)n * 768 + 512 + h * 32 + d4);
        Vt[d4 + 0][n] = v[0];
        Vt[d4 + 1][n] = v[1];
        Vt[d4 + 2][n] = v[2];
        Vt[d4 + 3][n] = v[3];
    }
    __syncthreads();
    int w = t >> 6, lane = t & 63;
    int cr = lane & 15, g = lane >> 4;
    int qb = qt * 32 + w * 16;
    // Q fragment: Q[qb+cr][g*8 .. +8)
    short8 qf = *(const short8*)(qkvb + (size_t)(qb + cr) * 768 + h * 32 + g * 8);
    // S = Q K^T : 32 j-tiles of 16 keys (K-dim = dh = 32, single MFMA each)
    f32x4 s[32];
    #pragma unroll
    for (int jt = 0; jt < 32; ++jt) {
        short8 kf = *(const short8*)(qkvb + (size_t)(jt * 16 + cr) * 768 + 256 + h * 32 + g * 8);
        f32x4 z = {0.f, 0.f, 0.f, 0.f};
        s[jt] = __builtin_amdgcn_mfma_f32_16x16x32_bf16(qf, kf, z, 0, 0, 0);
    }
    // softmax per q-row r (q = qb + 4g + r); row elems spread over (jt, cr)
    const float sc = 0.17677669529663687f;
    float m[4], l[4];
    #pragma unroll
    for (int r = 0; r < 4; ++r) {
        float mm = -1e30f;
        #pragma unroll
        for (int jt = 0; jt < 32; ++jt) mm = fmaxf(mm, s[jt][r]);
        #pragma unroll
        for (int off = 1; off < 16; off <<= 1) mm = fmaxf(mm, __shfl_xor(mm, off));
        m[r] = mm * sc;
    }
    #pragma unroll
    for (int r = 0; r < 4; ++r) {
        float ll = 0.f;
        #pragma unroll
        for (int jt = 0; jt < 32; ++jt) {
            float p = __expf(s[jt][r] * sc - m[r]);
            s[jt][r] = p;
            ll += p;
        }
        #pragma unroll
        for (int off = 1; off < 16; off <<= 1) ll += __shfl_xor(ll, off);
        l[r] = ll;
    }
    // O = P V, k-chunks of 32 keys; P transposed through per-wave LDS buffer
    f32x4 o0 = {0.f,0.f,0.f,0.f}, o1 = o0;
    #pragma unroll
    for (int c = 0; c < 16; ++c) {
        #pragma unroll
        for (int r = 0; r < 4; ++r) {
            Pb[w][4 * g + r][cr]      = f2bf(s[2 * c][r]);
            Pb[w][4 * g + r][16 + cr] = f2bf(s[2 * c + 1][r]);
        }
        short8 pa = *(const short8*)&Pb[w][cr][g * 8];           // P[cr][c*32+g*8..]
        short8 v0 = *(const short8*)&Vt[cr][c * 32 + g * 8];     // d = cr
        short8 v1 = *(const short8*)&Vt[16 + cr][c * 32 + g * 8];// d = 16+cr
        o0 = __builtin_amdgcn_mfma_f32_16x16x32_bf16(pa, v0, o0, 0, 0, 0);
        o1 = __builtin_amdgcn_mfma_f32_16x16x32_bf16(pa, v1, o1, 0, 0, 0);
    }
    #pragma unroll
    for (int r = 0; r < 4; ++r) {
        float inv = 1.f / l[r];
        int q = qb + 4 * g + r;
        short* op = obuf_bf + (size_t)q * 256 + h * 32;
        op[cr]      = f2bf(o0[r] * inv);
        op[16 + cr] = f2bf(o1[r] * inv);
    }
}

// ---------------- residual + LayerNorm (fp32 + bf16 out) ----------------
__global__ __launch_bounds__(64) void k_ln(const float* xr, const float* y,
                                           const float* __restrict__ g,
                                           const float* __restrict__ b,
                                           float* out, short* outb) {
    int n = blockIdx.x, lane = threadIdx.x;
    float4 xv = *(const float4*)(xr + (size_t)n * 256 + lane * 4);
    float4 yv = *(const float4*)(y + (size_t)n * 256 + lane * 4);
    float t0 = xv.x + yv.x, t1 = xv.y + yv.y, t2 = xv.z + yv.z, t3 = xv.w + yv.w;
    float s = t0 + t1 + t2 + t3;
    float sq = t0 * t0 + t1 * t1 + t2 * t2 + t3 * t3;
    s = wred_sum(s);
    sq = wred_sum(sq);
    float mean = s * (1.f / 256.f);
    float var = sq * (1.f / 256.f) - mean * mean;
    float rstd = rsqrtf(var + 1e-5f);
    float4 gv = *(const float4*)(g + lane * 4);
    float4 bv = *(const float4*)(b + lane * 4);
    float r0 = (t0 - mean) * rstd * gv.x + bv.x;
    float r1 = (t1 - mean) * rstd * gv.y + bv.y;
    float r2 = (t2 - mean) * rstd * gv.z + bv.z;
    float r3 = (t3 - mean) * rstd * gv.w + bv.w;
    *(float4*)(out + (size_t)n * 256 + lane * 4) = make_float4(r0, r1, r2, r3);
    short4v ob; ob[0] = f2bf(r0); ob[1] = f2bf(r1); ob[2] = f2bf(r2); ob[3] = f2bf(r3);
    *(short4v*)(outb + (size_t)n * 256 + lane * 4) = ob;
}

// ---------------- alpha head ----------------
__global__ __launch_bounds__(64) void k_alpha(const float* __restrict__ g,
                                              const float* __restrict__ A2,
                                              const float* __restrict__ a2b,
                                              float* __restrict__ alpha) {
    int n = blockIdx.x, lane = threadIdx.x;
    float4 gv = *(const float4*)(g + (size_t)n * 256 + lane * 4);
    float4 av = *(const float4*)(A2 + lane * 4);
    float s = gv.x * av.x + gv.y * av.y + gv.z * av.z + gv.w * av.w;
    s = wred_sum(s);
    if (lane == 0) {
        float ah = s + a2b[0];
        alpha[n] = 1.2f + 2.3f / (1.f + __expf(-ah));
    }
}

// ---------------- CSOCRG kernel smoothing ----------------
__global__ __launch_bounds__(256) void k_kern(const float* __restrict__ latent,
                                              const float* __restrict__ alpha,
                                              float* __restrict__ out,
                                              short* __restrict__ outb) {
    __shared__ float wl[512];
    __shared__ float partial[4];
    int i = blockIdx.x, t = threadIdx.x;
    float ai = alpha[i];
    float w0, w1;
    {
        int j = t;
        float dd = fabsf((float)(i - j)) + 1e-4f;
        float ap = 0.5f * (ai + alpha[j]);
        w0 = exp2f(-ap * __log2f(dd) - dd * 0.048089834696298776f); // log2(e)/30
        j = t + 256;
        dd = fabsf((float)(i - j)) + 1e-4f;
        ap = 0.5f * (ai + alpha[j]);
        w1 = exp2f(-ap * __log2f(dd) - dd * 0.048089834696298776f);
    }
    wl[t] = w0; wl[t + 256] = w1;
    float s = wred_sum(w0 + w1);
    if ((t & 63) == 0) partial[t >> 6] = s;
    __syncthreads();
    float S = partial[0] + partial[1] + partial[2] + partial[3];
    float inv = 1.f / (S + 1e-8f);
    float acc = 0.f;
    #pragma unroll 4
    for (int j = 0; j < 512; ++j) acc += wl[j] * latent[(size_t)j * 256 + t];
    float v = acc * inv;
    out[(size_t)i * 256 + t] = v;
    outb[(size_t)i * 256 + t] = f2bf(v);
}

// ---------------- distogram v2: 4 i's per wave, F2 frags reused ----------------
__global__ __launch_bounds__(256) void k_disto2(const float* __restrict__ hi,
                                                const float* __restrict__ hj,
                                                const short* __restrict__ F2bf,
                                                const float* __restrict__ f2b,
                                                float* __restrict__ out) {
    __shared__ __align__(16) float hjs[16][260];
    int jt = blockIdx.x, it = blockIdx.y;
    int j0 = jt * 16;
    int t = threadIdx.x;
    for (int q = t; q < 1024; q += 256) {  // 16 rows x 64 float4
        int r = q >> 6, c = (q & 63) << 2;
        float4 v = *(const float4*)(hj + (size_t)(j0 + r) * 256 + c);
        *(float4*)&hjs[r][c] = v;
    }
    __syncthreads();
    int w = t >> 6, lane = t & 63;
    int cr = lane & 15, g = lane >> 4;
    int i0 = it * 16 + w * 4;
    float bb[4];
    #pragma unroll
    for (int c = 0; c < 4; ++c) bb[c] = f2b[c * 16 + cr];
    f32x4 acc[4][4];
    #pragma unroll
    for (int ii = 0; ii < 4; ++ii)
        #pragma unroll
        for (int c = 0; c < 4; ++c) acc[ii][c] = (f32x4){0.f,0.f,0.f,0.f};
    #pragma unroll 1
    for (int ks = 0; ks < 8; ++ks) {
        int kb = ks * 32 + g * 8;
        short8 B[4];
        #pragma unroll
        for (int c = 0; c < 4; ++c)
            B[c] = *(const short8*)(F2bf + (size_t)(c * 16 + cr) * 256 + kb);
        float4 ja = *(const float4*)&hjs[cr][kb];
        float4 jb = *(const float4*)&hjs[cr][kb + 4];
        #pragma unroll
        for (int ii = 0; ii < 4; ++ii) {
            const float* hr = hi + (size_t)(i0 + ii) * 256 + kb;
            float4 ha = *(const float4*)(hr);
            float4 hb = *(const float4*)(hr + 4);
            short8 af;
            af[0] = f2bf(gelu_t(ha.x + ja.x));
            af[1] = f2bf(gelu_t(ha.y + ja.y));
            af[2] = f2bf(gelu_t(ha.z + ja.z));
            af[3] = f2bf(gelu_t(ha.w + ja.w));
            af[4] = f2bf(gelu_t(hb.x + jb.x));
            af[5] = f2bf(gelu_t(hb.y + jb.y));
            af[6] = f2bf(gelu_t(hb.z + jb.z));
            af[7] = f2bf(gelu_t(hb.w + jb.w));
            #pragma unroll
            for (int c = 0; c < 4; ++c)
                acc[ii][c] = __builtin_amdgcn_mfma_f32_16x16x32_bf16(af, B[c], acc[ii][c], 0, 0, 0);
        }
    }
    #pragma unroll
    for (int ii = 0; ii < 4; ++ii) {
        #pragma unroll
        for (int r = 0; r < 4; ++r) {
            int jl = g * 4 + r;
            float* op = out + ((size_t)(i0 + ii) * 512 + j0 + jl) * 64;
            op[cr]      = acc[ii][0][r] + bb[0];
            op[cr + 16] = acc[ii][1][r] + bb[1];
            op[cr + 32] = acc[ii][2][r] + bb[2];
            op[cr + 48] = acc[ii][3][r] + bb[3];
        }
    }
}

// ---------------- torsion head ----------------
__global__ __launch_bounds__(64) void k_torsion(const float* __restrict__ g,
                                                const float* __restrict__ T2,
                                                const float* __restrict__ t2b,
                                                float* __restrict__ phi,
                                                float* __restrict__ psi) {
    int n = blockIdx.x, lane = threadIdx.x;
    float4 gv = *(const float4*)(g + (size_t)n * 256 + lane * 4);
    float4 w0 = *(const float4*)(T2 + lane * 4);
    float4 w1 = *(const float4*)(T2 + 256 + lane * 4);
    float s0 = gv.x * w0.x + gv.y * w0.y + gv.z * w0.z + gv.w * w0.w;
    float s1 = gv.x * w1.x + gv.y * w1.y + gv.z * w1.z + gv.w * w1.w;
    s0 = wred_sum(s0);
    s1 = wred_sum(s1);
    if (lane == 0) {
        phi[n] = tanhf(s0 + t2b[0]) * 3.14159265358979323846f;
        psi[n] = tanhf(s1 + t2b[1]) * 3.14159265358979323846f;
    }
}

// ---------------- diffusion init (closed form) ----------------
__global__ __launch_bounds__(64) void k_diffusion(const float* __restrict__ latent,
                                                  const float* __restrict__ Cp,
                                                  const float* __restrict__ cpb,
                                                  const float* __restrict__ noise,
                                                  float* __restrict__ xc) {
    int n = blockIdx.x, lane = threadIdx.x;
    float4 lv = *(const float4*)(latent + (size_t)n * 256 + lane * 4);
    const float CN = 40320.0f / 16777216.0f;  // 8!/8^8
    float s[3];
    #pragma unroll
    for (int c = 0; c < 3; ++c) {
        float4 w = *(const float4*)(Cp + c * 256 + lane * 4);
        float v = lv.x * w.x + lv.y * w.y + lv.z * w.z + lv.w * w.w;
        s[c] = wred_sum(v);
    }
    if (lane == 0) {
        #pragma unroll
        for (int c = 0; c < 3; ++c) {
            float tg = s[c] + cpb[c];
            xc[n * 3 + c] = CN * noise[n * 3 + c] + (1.f - CN) * tg;
        }
    }
}

extern "C" void kernel_launch(void* const* d_in, const int* in_sizes, int n_in,
                              void* d_out, int out_size, void* d_ws, size_t ws_size,
                              hipStream_t stream) {
    const int*   tokens = (const int*)d_in[0];
    const float* emb  = (const float*)d_in[1];
    const float* Wqkv = (const float*)d_in[2];
    const float* bqkv = (const float*)d_in[3];
    const float* Wo   = (const float*)d_in[4];
    const float* bo   = (const float*)d_in[5];
    const float* g1   = (const float*)d_in[6];
    const float* be1  = (const float*)d_in[7];
    const float* W1   = (const float*)d_in[8];
    const float* b1   = (const float*)d_in[9];
    const float* W2   = (const float*)d_in[10];
    const float* b2   = (const float*)d_in[11];
    const float* g2   = (const float*)d_in[12];
    const float* be2  = (const float*)d_in[13];
    const float* A1   = (const float*)d_in[14];
    const float* a1b  = (const float*)d_in[15];
    const float* A2   = (const float*)d_in[16];
    const float* a2b  = (const float*)d_in[17];
    const float* Cf   = (const float*)d_in[18];
    const float* cb   = (const float*)d_in[19];
    const float* F1   = (const float*)d_in[20];
    const float* f1b  = (const float*)d_in[21];
    const float* F2   = (const float*)d_in[22];
    const float* f2b  = (const float*)d_in[23];
    const float* T1   = (const float*)d_in[24];
    const float* t1b  = (const float*)d_in[25];
    const float* T2   = (const float*)d_in[26];
    const float* t2b  = (const float*)d_in[27];
    const float* Cp   = (const float*)d_in[28];
    const float* cpb  = (const float*)d_in[29];
    const float* noise= (const float*)d_in[30];

    float* ws   = (float*)d_ws;
    float* x    = ws;                 // 131072
    float* y2   = ws + 131072;        // 131072
    float* gbuf = ws + 262144;        // 131072
    float* hi   = ws + 393216;        // 131072
    float* hj   = ws + 524288;        // 131072
    short* S    = (short*)(ws + 655360);
    short* x_bf    = S;               // 131072 shorts
    short* obuf_bf = S + 131072;      // 131072
    short* h1_bf   = S + 262144;      // 524288
    short* hh_bf   = S + 786432;      // 131072
    short* lat_bf  = S + 917504;      // 131072
    short* F2bf    = S + 1048576;     // 16384
    short* qkv_bf  = S + 1064960;     // 393216
    short* Wqkv_bf = S + 1458176;     // 1179648
    short* Wo_bf   = S + 2637824;     // 393216
    short* W1_bf   = S + 3031040;     // 1572864
    short* W2_bf   = S + 4603904;     // 1572864
    short* A1_bf   = S + 6176768;     // 65536
    short* Cf_bf   = S + 6242304;     // 65536
    short* F1_bf   = S + 6307840;     // 131072
    short* T1_bf   = S + 6438912;     // 65536

    float* out = (float*)d_out;
    float* o_latent  = out;                // 131072
    float* o_alpha   = out + 131072;       // 512
    float* o_contact = out + 131584;       // 262144
    float* o_disto   = out + 393728;       // 16777216
    float* o_phi     = out + 17170944;     // 512
    float* o_psi     = out + 17171456;     // 512
    float* o_xc      = out + 17171968;     // 1536

    CvtPack p;
    p.s[0] = Wqkv; p.d[0] = Wqkv_bf; p.n[0] = 1179648;
    p.s[1] = Wo;   p.d[1] = Wo_bf;   p.n[1] = 393216;
    p.s[2] = W1;   p.d[2] = W1_bf;   p.n[2] = 1572864;
    p.s[3] = W2;   p.d[3] = W2_bf;   p.n[3] = 1572864;
    p.s[4] = A1;   p.d[4] = A1_bf;   p.n[4] = 65536;
    p.s[5] = Cf;   p.d[5] = Cf_bf;   p.n[5] = 65536;
    p.s[6] = F1;   p.d[6] = F1_bf;   p.n[6] = 131072;
    p.s[7] = T1;   p.d[7] = T1_bf;   p.n[7] = 65536;
    p.s[8] = F2;   p.d[8] = F2bf;    p.n[8] = 16384;
    k_cvt_all<<<512, 256, 0, stream>>>(p);

    k_embed<<<512, 256, 0, stream>>>(tokens, emb, x, x_bf);

    for (int l = 0; l < 6; ++l) {
        k_gemm_bf<<<dim3(24, 16), 64, 0, stream>>>(x_bf, Wqkv_bf + (size_t)l * 196608,
            bqkv + l * 768, nullptr, qkv_bf, 768, 256, 256, 0);
        k_attn2<<<dim3(8, 16), 128, 0, stream>>>(qkv_bf, obuf_bf);
        k_gemm_bf<<<dim3(8, 16), 64, 0, stream>>>(obuf_bf, Wo_bf + (size_t)l * 65536,
            bo + l * 256, y2, nullptr, 256, 256, 256, 0);
        k_ln<<<512, 64, 0, stream>>>(x, y2, g1 + l * 256, be1 + l * 256, x, x_bf);
        k_gemm_bf<<<dim3(32, 16), 64, 0, stream>>>(x_bf, W1_bf + (size_t)l * 262144,
            b1 + l * 1024, nullptr, h1_bf, 1024, 256, 256, 1);
        k_gemm_bf<<<dim3(8, 16), 64, 0, stream>>>(h1_bf, W2_bf + (size_t)l * 262144,
            b2 + l * 256, y2, nullptr, 256, 1024, 1024, 0);
        k_ln<<<512, 64, 0, stream>>>(x, y2, g2 + l * 256, be2 + l * 256, x, x_bf);
    }

    // alpha head (pre-smoothing latent)
    k_gemm_bf<<<dim3(8, 16), 64, 0, stream>>>(x_bf, A1_bf, a1b, gbuf, nullptr,
                                              256, 256, 256, 2);
    k_alpha<<<512, 64, 0, stream>>>(gbuf, A2, a2b, o_alpha);
    // CSOCRG smoothing -> latent output (fp32 + bf16)
    k_kern<<<512, 256, 0, stream>>>(x, o_alpha, o_latent, lat_bf);
    // contact head
    k_gemm_bf<<<dim3(8, 16), 64, 0, stream>>>(lat_bf, Cf_bf, cb, nullptr, hh_bf,
                                              256, 256, 256, 0);
    k_gemm_bf<<<dim3(16, 16), 64, 0, stream>>>(hh_bf, hh_bf, nullptr, o_contact, nullptr,
                                               512, 256, 256, 3);
    // distogram head
    k_gemm_bf<<<dim3(8, 16), 64, 0, stream>>>(lat_bf, F1_bf, f1b, hi, nullptr,
                                              256, 256, 512, 0);
    k_gemm_bf<<<dim3(8, 16), 64, 0, stream>>>(lat_bf, F1_bf + 256, nullptr, hj, nullptr,
                                              256, 256, 512, 0);
    k_disto2<<<dim3(32, 32), 256, 0, stream>>>(hi, hj, F2bf, f2b, o_disto);
    // torsion head
    k_gemm_bf<<<dim3(8, 16), 64, 0, stream>>>(lat_bf, T1_bf, t1b, gbuf, nullptr,
                                              256, 256, 256, 2);
    k_torsion<<<512, 64, 0, stream>>>(gbuf, T2, t2b, o_phi, o_psi);
    // diffusion init
    k_diffusion<<<512, 64, 0, stream>>>(o_latent, Cp, cpb, noise, o_xc);
}

// Round 5
// 389.787 us; speedup vs baseline: 2.8636x; 1.2079x over previous
//
#include <hip/hip_runtime.h>
#include <hip/hip_bf16.h>

#define DEV __device__ __forceinline__

typedef float f32x4 __attribute__((ext_vector_type(4)));
typedef short short8 __attribute__((ext_vector_type(8)));
typedef short short4v __attribute__((ext_vector_type(4)));

DEV short f2bf(float f) {
    union { float f; unsigned u; } c; c.f = f;
    unsigned r = (c.u + 0x7FFFu + ((c.u >> 16) & 1u)) >> 16;  // RNE
    return (short)r;
}

DEV short f2bf_n(float f) {   // native HW convert (RNE)
    __hip_bfloat16 b = __float2bfloat16(f);
    union { __hip_bfloat16 b; short s; } c; c.b = b;
    return c.s;
}

// tanh-approx gelu, exp2 form: max |err| vs erf-gelu ~2e-4
DEV float gelu_t(float x) {
    float x2 = x * x;
    float y = x * (0.7978845608f + 0.0356774081f * x2);
    float e = exp2f(-2.8853900817779268f * fabsf(y));  // 2*log2(e)
    float t = (1.f - e) * __frcp_rn(1.f + e);          // tanh(|y|)
    t = copysignf(t, y);
    return 0.5f * x * (1.f + t);
}

DEV float wred_sum(float v) {
    #pragma unroll
    for (int off = 1; off < 64; off <<= 1) v += __shfl_xor(v, off);
    return v;
}

// ---------------- bulk fp32 -> bf16 conversion (9 segments) ----------------
struct CvtPack {
    const float* s[9];
    short* d[9];
    int n[9];
};
__global__ __launch_bounds__(256) void k_cvt_all(CvtPack p) {
    #pragma unroll 1
    for (int seg = 0; seg < 9; ++seg) {
        int n4 = p.n[seg] >> 2;
        const float4* src = (const float4*)p.s[seg];
        short4v* dst = (short4v*)p.d[seg];
        for (int i = blockIdx.x * 256 + threadIdx.x; i < n4; i += gridDim.x * 256) {
            float4 v = src[i];
            short4v o;
            o[0] = f2bf(v.x); o[1] = f2bf(v.y); o[2] = f2bf(v.z); o[3] = f2bf(v.w);
            dst[i] = o;
        }
    }
}

// ---------------- embedding + positional encoding (fp32 + bf16) ----------------
__global__ __launch_bounds__(256) void k_embed(const int* __restrict__ tokens,
                                               const float* __restrict__ emb,
                                               float* __restrict__ x,
                                               short* __restrict__ xb) {
    int n = blockIdx.x, d = threadIdx.x;
    int tok = tokens[n];
    float div = expf((float)((d >> 1) * 2) * -0.035977892079030837f); // -ln(10000)/256
    float arg = (float)n * div;
    float pe = (d & 1) ? cosf(arg) : sinf(arg);
    float v = emb[tok * 256 + d] + pe;
    x[n * 256 + d] = v;
    xb[n * 256 + d] = f2bf(v);
}

// ---------------- bf16 MFMA GEMM, 16x16 tile per wave ----------------
// A bf16 [N][K] row-major, W bf16 rows at stride ldw. grid = (M/16, N/16), 64 thr.
// Optional: fp32 out, bf16 out, vt transpose (cols 512..767 -> vt[(m-512)*512+row], bf16).
__global__ __launch_bounds__(64) void k_gemm16(const short* __restrict__ A,
                                               const short* __restrict__ W,
                                               const float* __restrict__ bias,
                                               float* __restrict__ outf,
                                               short* __restrict__ outb,
                                               short* __restrict__ vt,
                                               int M, int K, int ldw, int act) {
    int m0 = blockIdx.x * 16, n0 = blockIdx.y * 16;
    int lane = threadIdx.x;
    int cr = lane & 15, g = lane >> 4;
    const short* a0 = A + (size_t)(n0 + cr) * K + g * 8;
    const short* b0 = W + (size_t)(m0 + cr) * ldw + g * 8;
    f32x4 acc = {0.f, 0.f, 0.f, 0.f};
    #pragma unroll 8
    for (int k = 0; k < K; k += 32) {
        short8 av = *(const short8*)(a0 + k);
        short8 bv = *(const short8*)(b0 + k);
        acc = __builtin_amdgcn_mfma_f32_16x16x32_bf16(av, bv, acc, 0, 0, 0);
    }
    float bb = bias ? bias[m0 + cr] : 0.f;
    int m = m0 + cr;
    #pragma unroll
    for (int r = 0; r < 4; ++r) {
        int row = n0 + g * 4 + r;
        float v = acc[r] + bb;
        if (act == 1) v = fmaxf(v, 0.f);
        else if (act == 2) v = gelu_t(v);
        else if (act == 3) v = 1.f / (1.f + __expf(-v));
        if (outf) outf[(size_t)row * M + m] = v;
        if (outb) outb[(size_t)row * M + m] = f2bf(v);
        if (vt && m >= 512) vt[(size_t)(m - 512) * 512 + row] = f2bf(v);
    }
}

// ---------------- MFMA flash attention v3: no staging, V^T precomputed ----------
// qkvb bf16 [512][768]; vt bf16 [256][512] (d-major). 64 thr, grid (8 h, 32 qt).
__global__ __launch_bounds__(64) void k_attn3(const short* __restrict__ qkvb,
                                              const short* __restrict__ vt,
                                              short* __restrict__ obuf_bf) {
    __shared__ __align__(16) short Pb[16][40];
    int h = blockIdx.x, qt = blockIdx.y;
    int lane = threadIdx.x;
    int cr = lane & 15, g = lane >> 4;
    int qb = qt * 16;
    short8 qf = *(const short8*)(qkvb + (size_t)(qb + cr) * 768 + h * 32 + g * 8);
    // S = Q K^T : 32 j-tiles of 16 keys (K-dim = dh = 32, one MFMA each)
    f32x4 s[32];
    #pragma unroll
    for (int jt = 0; jt < 32; ++jt) {
        short8 kf = *(const short8*)(qkvb + (size_t)(jt * 16 + cr) * 768 + 256 + h * 32 + g * 8);
        f32x4 z = {0.f, 0.f, 0.f, 0.f};
        s[jt] = __builtin_amdgcn_mfma_f32_16x16x32_bf16(qf, kf, z, 0, 0, 0);
    }
    const float sc = 0.17677669529663687f; // 1/sqrt(32)
    float m[4], l[4];
    #pragma unroll
    for (int r = 0; r < 4; ++r) {
        float mm = -1e30f;
        #pragma unroll
        for (int jt = 0; jt < 32; ++jt) mm = fmaxf(mm, s[jt][r]);
        #pragma unroll
        for (int off = 1; off < 16; off <<= 1) mm = fmaxf(mm, __shfl_xor(mm, off));
        m[r] = mm * sc;
    }
    #pragma unroll
    for (int r = 0; r < 4; ++r) {
        float ll = 0.f;
        #pragma unroll
        for (int jt = 0; jt < 32; ++jt) {
            float p = __expf(s[jt][r] * sc - m[r]);
            s[jt][r] = p;
            ll += p;
        }
        #pragma unroll
        for (int off = 1; off < 16; off <<= 1) ll += __shfl_xor(ll, off);
        l[r] = ll;
    }
    // O = P V over 16 key-chunks of 32; P transposed through per-wave LDS
    const short* vth0 = vt + (size_t)(h * 32 + cr) * 512;
    const short* vth1 = vt + (size_t)(h * 32 + 16 + cr) * 512;
    f32x4 o0 = {0.f,0.f,0.f,0.f}, o1 = o0;
    #pragma unroll
    for (int c = 0; c < 16; ++c) {
        #pragma unroll
        for (int r = 0; r < 4; ++r) {
            Pb[4 * g + r][cr]      = f2bf(s[2 * c][r]);
            Pb[4 * g + r][16 + cr] = f2bf(s[2 * c + 1][r]);
        }
        short8 pa = *(const short8*)&Pb[cr][g * 8];
        short8 v0 = *(const short8*)(vth0 + c * 32 + g * 8);
        short8 v1 = *(const short8*)(vth1 + c * 32 + g * 8);
        o0 = __builtin_amdgcn_mfma_f32_16x16x32_bf16(pa, v0, o0, 0, 0, 0);
        o1 = __builtin_amdgcn_mfma_f32_16x16x32_bf16(pa, v1, o1, 0, 0, 0);
    }
    #pragma unroll
    for (int r = 0; r < 4; ++r) {
        float inv = 1.f / l[r];
        int q = qb + 4 * g + r;
        short* op = obuf_bf + (size_t)q * 256 + h * 32;
        op[cr]      = f2bf(o0[r] * inv);
        op[16 + cr] = f2bf(o1[r] * inv);
    }
}

// ---------------- residual + LayerNorm (fp32 + bf16 out) ----------------
__global__ __launch_bounds__(64) void k_ln(const float* xr, const float* y,
                                           const float* __restrict__ g,
                                           const float* __restrict__ b,
                                           float* out, short* outb) {
    int n = blockIdx.x, lane = threadIdx.x;
    float4 xv = *(const float4*)(xr + (size_t)n * 256 + lane * 4);
    float4 yv = *(const float4*)(y + (size_t)n * 256 + lane * 4);
    float t0 = xv.x + yv.x, t1 = xv.y + yv.y, t2 = xv.z + yv.z, t3 = xv.w + yv.w;
    float s = t0 + t1 + t2 + t3;
    float sq = t0 * t0 + t1 * t1 + t2 * t2 + t3 * t3;
    s = wred_sum(s);
    sq = wred_sum(sq);
    float mean = s * (1.f / 256.f);
    float var = sq * (1.f / 256.f) - mean * mean;
    float rstd = rsqrtf(var + 1e-5f);
    float4 gv = *(const float4*)(g + lane * 4);
    float4 bv = *(const float4*)(b + lane * 4);
    float r0 = (t0 - mean) * rstd * gv.x + bv.x;
    float r1 = (t1 - mean) * rstd * gv.y + bv.y;
    float r2 = (t2 - mean) * rstd * gv.z + bv.z;
    float r3 = (t3 - mean) * rstd * gv.w + bv.w;
    *(float4*)(out + (size_t)n * 256 + lane * 4) = make_float4(r0, r1, r2, r3);
    short4v ob; ob[0] = f2bf(r0); ob[1] = f2bf(r1); ob[2] = f2bf(r2); ob[3] = f2bf(r3);
    *(short4v*)(outb + (size_t)n * 256 + lane * 4) = ob;
}

// ---------------- alpha head ----------------
__global__ __launch_bounds__(64) void k_alpha(const float* __restrict__ g,
                                              const float* __restrict__ A2,
                                              const float* __restrict__ a2b,
                                              float* __restrict__ alpha) {
    int n = blockIdx.x, lane = threadIdx.x;
    float4 gv = *(const float4*)(g + (size_t)n * 256 + lane * 4);
    float4 av = *(const float4*)(A2 + lane * 4);
    float s = gv.x * av.x + gv.y * av.y + gv.z * av.z + gv.w * av.w;
    s = wred_sum(s);
    if (lane == 0) {
        float ah = s + a2b[0];
        alpha[n] = 1.2f + 2.3f / (1.f + __expf(-ah));
    }
}

// ---------------- CSOCRG kernel smoothing ----------------
__global__ __launch_bounds__(256) void k_kern(const float* __restrict__ latent,
                                              const float* __restrict__ alpha,
                                              float* __restrict__ out,
                                              short* __restrict__ outb) {
    __shared__ float wl[512];
    __shared__ float partial[4];
    int i = blockIdx.x, t = threadIdx.x;
    float ai = alpha[i];
    float w0, w1;
    {
        int j = t;
        float dd = fabsf((float)(i - j)) + 1e-4f;
        float ap = 0.5f * (ai + alpha[j]);
        w0 = exp2f(-ap * __log2f(dd) - dd * 0.048089834696298776f); // log2(e)/30
        j = t + 256;
        dd = fabsf((float)(i - j)) + 1e-4f;
        ap = 0.5f * (ai + alpha[j]);
        w1 = exp2f(-ap * __log2f(dd) - dd * 0.048089834696298776f);
    }
    wl[t] = w0; wl[t + 256] = w1;
    float s = wred_sum(w0 + w1);
    if ((t & 63) == 0) partial[t >> 6] = s;
    __syncthreads();
    float S = partial[0] + partial[1] + partial[2] + partial[3];
    float inv = 1.f / (S + 1e-8f);
    float acc = 0.f;
    #pragma unroll 4
    for (int j = 0; j < 512; ++j) acc += wl[j] * latent[(size_t)j * 256 + t];
    float v = acc * inv;
    out[(size_t)i * 256 + t] = v;
    outb[(size_t)i * 256 + t] = f2bf(v);
}

// ---------------- distogram v3: 2 i's per wave, 2x grid for occupancy ----------
// grid = (32 jt, 64 it), 256 threads (4 waves). wave w: i = it*8 + w*2 + {0,1}.
__global__ __launch_bounds__(256) void k_disto3(const float* __restrict__ hi,
                                                const float* __restrict__ hj,
                                                const short* __restrict__ F2bf,
                                                const float* __restrict__ f2b,
                                                float* __restrict__ out) {
    __shared__ __align__(16) float hjs[16][260];
    int jt = blockIdx.x, it = blockIdx.y;
    int j0 = jt * 16;
    int t = threadIdx.x;
    for (int q = t; q < 1024; q += 256) {  // 16 rows x 64 float4
        int r = q >> 6, c = (q & 63) << 2;
        float4 v = *(const float4*)(hj + (size_t)(j0 + r) * 256 + c);
        *(float4*)&hjs[r][c] = v;
    }
    __syncthreads();
    int w = t >> 6, lane = t & 63;
    int cr = lane & 15, g = lane >> 4;
    int i0 = it * 8 + w * 2;
    float bb[4];
    #pragma unroll
    for (int c = 0; c < 4; ++c) bb[c] = f2b[c * 16 + cr];
    f32x4 acc[2][4];
    #pragma unroll
    for (int ii = 0; ii < 2; ++ii)
        #pragma unroll
        for (int c = 0; c < 4; ++c) acc[ii][c] = (f32x4){0.f,0.f,0.f,0.f};
    #pragma unroll 1
    for (int ks = 0; ks < 8; ++ks) {
        int kb = ks * 32 + g * 8;
        short8 B[4];
        #pragma unroll
        for (int c = 0; c < 4; ++c)
            B[c] = *(const short8*)(F2bf + (size_t)(c * 16 + cr) * 256 + kb);
        float4 ja = *(const float4*)&hjs[cr][kb];
        float4 jb = *(const float4*)&hjs[cr][kb + 4];
        #pragma unroll
        for (int ii = 0; ii < 2; ++ii) {
            const float* hr = hi + (size_t)(i0 + ii) * 256 + kb;
            float4 ha = *(const float4*)(hr);
            float4 hb = *(const float4*)(hr + 4);
            short8 af;
            af[0] = f2bf_n(gelu_t(ha.x + ja.x));
            af[1] = f2bf_n(gelu_t(ha.y + ja.y));
            af[2] = f2bf_n(gelu_t(ha.z + ja.z));
            af[3] = f2bf_n(gelu_t(ha.w + ja.w));
            af[4] = f2bf_n(gelu_t(hb.x + jb.x));
            af[5] = f2bf_n(gelu_t(hb.y + jb.y));
            af[6] = f2bf_n(gelu_t(hb.z + jb.z));
            af[7] = f2bf_n(gelu_t(hb.w + jb.w));
            #pragma unroll
            for (int c = 0; c < 4; ++c)
                acc[ii][c] = __builtin_amdgcn_mfma_f32_16x16x32_bf16(af, B[c], acc[ii][c], 0, 0, 0);
        }
    }
    #pragma unroll
    for (int ii = 0; ii < 2; ++ii) {
        #pragma unroll
        for (int r = 0; r < 4; ++r) {
            int jl = g * 4 + r;
            float* op = out + ((size_t)(i0 + ii) * 512 + j0 + jl) * 64;
            op[cr]      = acc[ii][0][r] + bb[0];
            op[cr + 16] = acc[ii][1][r] + bb[1];
            op[cr + 32] = acc[ii][2][r] + bb[2];
            op[cr + 48] = acc[ii][3][r] + bb[3];
        }
    }
}

// ---------------- torsion head ----------------
__global__ __launch_bounds__(64) void k_torsion(const float* __restrict__ g,
                                                const float* __restrict__ T2,
                                                const float* __restrict__ t2b,
                                                float* __restrict__ phi,
                                                float* __restrict__ psi) {
    int n = blockIdx.x, lane = threadIdx.x;
    float4 gv = *(const float4*)(g + (size_t)n * 256 + lane * 4);
    float4 w0 = *(const float4*)(T2 + lane * 4);
    float4 w1 = *(const float4*)(T2 + 256 + lane * 4);
    float s0 = gv.x * w0.x + gv.y * w0.y + gv.z * w0.z + gv.w * w0.w;
    float s1 = gv.x * w1.x + gv.y * w1.y + gv.z * w1.z + gv.w * w1.w;
    s0 = wred_sum(s0);
    s1 = wred_sum(s1);
    if (lane == 0) {
        phi[n] = tanhf(s0 + t2b[0]) * 3.14159265358979323846f;
        psi[n] = tanhf(s1 + t2b[1]) * 3.14159265358979323846f;
    }
}

// ---------------- diffusion init (closed form) ----------------
__global__ __launch_bounds__(64) void k_diffusion(const float* __restrict__ latent,
                                                  const float* __restrict__ Cp,
                                                  const float* __restrict__ cpb,
                                                  const float* __restrict__ noise,
                                                  float* __restrict__ xc) {
    int n = blockIdx.x, lane = threadIdx.x;
    float4 lv = *(const float4*)(latent + (size_t)n * 256 + lane * 4);
    const float CN = 40320.0f / 16777216.0f;  // 8!/8^8
    float s[3];
    #pragma unroll
    for (int c = 0; c < 3; ++c) {
        float4 w = *(const float4*)(Cp + c * 256 + lane * 4);
        float v = lv.x * w.x + lv.y * w.y + lv.z * w.z + lv.w * w.w;
        s[c] = wred_sum(v);
    }
    if (lane == 0) {
        #pragma unroll
        for (int c = 0; c < 3; ++c) {
            float tg = s[c] + cpb[c];
            xc[n * 3 + c] = CN * noise[n * 3 + c] + (1.f - CN) * tg;
        }
    }
}

extern "C" void kernel_launch(void* const* d_in, const int* in_sizes, int n_in,
                              void* d_out, int out_size, void* d_ws, size_t ws_size,
                              hipStream_t stream) {
    const int*   tokens = (const int*)d_in[0];
    const float* emb  = (const float*)d_in[1];
    const float* Wqkv = (const float*)d_in[2];
    const float* bqkv = (const float*)d_in[3];
    const float* Wo   = (const float*)d_in[4];
    const float* bo   = (const float*)d_in[5];
    const float* g1   = (const float*)d_in[6];
    const float* be1  = (const float*)d_in[7];
    const float* W1   = (const float*)d_in[8];
    const float* b1   = (const float*)d_in[9];
    const float* W2   = (const float*)d_in[10];
    const float* b2   = (const float*)d_in[11];
    const float* g2   = (const float*)d_in[12];
    const float* be2  = (const float*)d_in[13];
    const float* A1   = (const float*)d_in[14];
    const float* a1b  = (const float*)d_in[15];
    const float* A2   = (const float*)d_in[16];
    const float* a2b  = (const float*)d_in[17];
    const float* Cf   = (const float*)d_in[18];
    const float* cb   = (const float*)d_in[19];
    const float* F1   = (const float*)d_in[20];
    const float* f1b  = (const float*)d_in[21];
    const float* F2   = (const float*)d_in[22];
    const float* f2b  = (const float*)d_in[23];
    const float* T1   = (const float*)d_in[24];
    const float* t1b  = (const float*)d_in[25];
    const float* T2   = (const float*)d_in[26];
    const float* t2b  = (const float*)d_in[27];
    const float* Cp   = (const float*)d_in[28];
    const float* cpb  = (const float*)d_in[29];
    const float* noise= (const float*)d_in[30];

    float* ws   = (float*)d_ws;
    float* x    = ws;                 // 131072
    float* y2   = ws + 131072;        // 131072
    float* gbuf = ws + 262144;        // 131072
    float* hi   = ws + 393216;        // 131072
    float* hj   = ws + 524288;        // 131072
    short* S    = (short*)(ws + 655360);
    short* x_bf    = S;               // 131072 shorts
    short* obuf_bf = S + 131072;      // 131072
    short* h1_bf   = S + 262144;      // 524288
    short* hh_bf   = S + 786432;      // 131072
    short* lat_bf  = S + 917504;      // 131072
    short* F2bf    = S + 1048576;     // 16384
    short* qkv_bf  = S + 1064960;     // 393216
    short* vt      = S + 1458176;     // 131072
    short* Wqkv_bf = S + 1589248;     // 1179648
    short* Wo_bf   = S + 2768896;     // 393216
    short* W1_bf   = S + 3162112;     // 1572864
    short* W2_bf   = S + 4734976;     // 1572864
    short* A1_bf   = S + 6307840;     // 65536
    short* Cf_bf   = S + 6373376;     // 65536
    short* F1_bf   = S + 6438912;     // 131072
    short* T1_bf   = S + 6569984;     // 65536

    float* out = (float*)d_out;
    float* o_latent  = out;                // 131072
    float* o_alpha   = out + 131072;       // 512
    float* o_contact = out + 131584;       // 262144
    float* o_disto   = out + 393728;       // 16777216
    float* o_phi     = out + 17170944;     // 512
    float* o_psi     = out + 17171456;     // 512
    float* o_xc      = out + 17171968;     // 1536

    CvtPack p;
    p.s[0] = Wqkv; p.d[0] = Wqkv_bf; p.n[0] = 1179648;
    p.s[1] = Wo;   p.d[1] = Wo_bf;   p.n[1] = 393216;
    p.s[2] = W1;   p.d[2] = W1_bf;   p.n[2] = 1572864;
    p.s[3] = W2;   p.d[3] = W2_bf;   p.n[3] = 1572864;
    p.s[4] = A1;   p.d[4] = A1_bf;   p.n[4] = 65536;
    p.s[5] = Cf;   p.d[5] = Cf_bf;   p.n[5] = 65536;
    p.s[6] = F1;   p.d[6] = F1_bf;   p.n[6] = 131072;
    p.s[7] = T1;   p.d[7] = T1_bf;   p.n[7] = 65536;
    p.s[8] = F2;   p.d[8] = F2bf;    p.n[8] = 16384;
    k_cvt_all<<<512, 256, 0, stream>>>(p);

    k_embed<<<512, 256, 0, stream>>>(tokens, emb, x, x_bf);

    for (int l = 0; l < 6; ++l) {
        k_gemm16<<<dim3(48, 32), 64, 0, stream>>>(x_bf, Wqkv_bf + (size_t)l * 196608,
            bqkv + l * 768, nullptr, qkv_bf, vt, 768, 256, 256, 0);
        k_attn3<<<dim3(8, 32), 64, 0, stream>>>(qkv_bf, vt, obuf_bf);
        k_gemm16<<<dim3(16, 32), 64, 0, stream>>>(obuf_bf, Wo_bf + (size_t)l * 65536,
            bo + l * 256, y2, nullptr, nullptr, 256, 256, 256, 0);
        k_ln<<<512, 64, 0, stream>>>(x, y2, g1 + l * 256, be1 + l * 256, x, x_bf);
        k_gemm16<<<dim3(64, 32), 64, 0, stream>>>(x_bf, W1_bf + (size_t)l * 262144,
            b1 + l * 1024, nullptr, h1_bf, nullptr, 1024, 256, 256, 1);
        k_gemm16<<<dim3(16, 32), 64, 0, stream>>>(h1_bf, W2_bf + (size_t)l * 262144,
            b2 + l * 256, y2, nullptr, nullptr, 256, 1024, 1024, 0);
        k_ln<<<512, 64, 0, stream>>>(x, y2, g2 + l * 256, be2 + l * 256, x, x_bf);
    }

    // alpha head (pre-smoothing latent)
    k_gemm16<<<dim3(16, 32), 64, 0, stream>>>(x_bf, A1_bf, a1b, gbuf, nullptr, nullptr,
                                              256, 256, 256, 2);
    k_alpha<<<512, 64, 0, stream>>>(gbuf, A2, a2b, o_alpha);
    // CSOCRG smoothing -> latent output (fp32 + bf16)
    k_kern<<<512, 256, 0, stream>>>(x, o_alpha, o_latent, lat_bf);
    // contact head
    k_gemm16<<<dim3(16, 32), 64, 0, stream>>>(lat_bf, Cf_bf, cb, nullptr, hh_bf, nullptr,
                                              256, 256, 256, 0);
    k_gemm16<<<dim3(32, 32), 64, 0, stream>>>(hh_bf, hh_bf, nullptr, o_contact, nullptr,
                                              nullptr, 512, 256, 256, 3);
    // distogram head
    k_gemm16<<<dim3(16, 32), 64, 0, stream>>>(lat_bf, F1_bf, f1b, hi, nullptr, nullptr,
                                              256, 256, 512, 0);
    k_gemm16<<<dim3(16, 32), 64, 0, stream>>>(lat_bf, F1_bf + 256, nullptr, hj, nullptr,
                                              nullptr, 256, 256, 512, 0);
    k_disto3<<<dim3(32, 64), 256, 0, stream>>>(hi, hj, F2bf, f2b, o_disto);
    // torsion head
    k_gemm16<<<dim3(16, 32), 64, 0, stream>>>(lat_bf, T1_bf, t1b, gbuf, nullptr, nullptr,
                                              256, 256, 256, 2);
    k_torsion<<<512, 64, 0, stream>>>(gbuf, T2, t2b, o_phi, o_psi);
    // diffusion init
    k_diffusion<<<512, 64, 0, stream>>>(o_latent, Cp, cpb, noise, o_xc);
}